// Round 4
// baseline (181.395 us; speedup 1.0000x reference)
//
#include <hip/hip_runtime.h>
#include <math.h>

#define B_N 8
#define IN_N 8
#define J_N 8
#define S_N 187
#define F_N 64
#define O_N 64
#define C_N 67
#define KS_N 15
#define SF_N (S_N * F_N)   // 11968
#define SF4_N (SF_N / 4)   // 2992 float4s per (b,i) plane
#define SQRT_SF 0.85467470f  // sqrt(187/256)

#define NT_SPL 12           // 1024-wide idx tiles (256 float4/block) covering SF_N
#define NCOMB 96            // combined blocks in k_mid2 (8*12)
#define NKT16 768           // ktqt16 blocks (64 bj * 12 stiles)
#define NXPR 768            // xprime blocks (12*64)
#define NMAXP 256           // maxabs partial blocks
#define FRAG_BJ 49152       // 12 stiles * 4096 halves per bj

typedef __attribute__((ext_vector_type(8))) _Float16 half8;
typedef __attribute__((ext_vector_type(4))) _Float16 half4;
typedef __attribute__((ext_vector_type(4))) float floatx4;

// ---------------- wave helpers (wave = 64) ----------------
__device__ __forceinline__ float wave_sum(float v) {
#pragma unroll
  for (int off = 32; off > 0; off >>= 1) v += __shfl_down(v, off, 64);
  return __shfl(v, 0, 64);
}
__device__ __forceinline__ float wave_max(float v) {
#pragma unroll
  for (int off = 32; off > 0; off >>= 1) v = fmaxf(v, __shfl_down(v, off, 64));
  return __shfl(v, 0, 64);
}
__device__ __forceinline__ float lane_bc(float v, int l) {
  return __int_as_float(__builtin_amdgcn_readlane(__float_as_int(v), l));
}
__device__ __forceinline__ float bspline(float d) {
  float t2 = fmaxf(2.f - d, 0.f);
  float t1 = fmaxf(1.f - d, 0.f);
  return t2 * t2 * t2 * (1.f / 6.f) - t1 * t1 * t1 * (4.f / 6.f);
}
__device__ __forceinline__ float get_inv095(const float* __restrict__ maxp) {
  int lane = threadIdx.x & 63;
  float m = 0.f;
#pragma unroll
  for (int k = 0; k < NMAXP / 64; k++) m = fmaxf(m, maxp[lane + k * 64]);
  return 0.95f / (wave_max(m) + 1e-8f);
}
// gate = (sqrtE/tau) * sigmoid((sqrtE-tau)/tv) from the 12 per-tile partials
__device__ __forceinline__ float gate_g(const float* __restrict__ esum_p, int bi, int j,
                                        const float* __restrict__ tau, float tv) {
  const float* p = esum_p + ((long)bi * 8 + j) * NT_SPL;
  float s = 0.f;
#pragma unroll
  for (int k = 0; k < NT_SPL; k++) s += p[k];
  float sE = sqrtf(s * (1.f / (float)SF_N) + 1e-8f);
  float ta = fabsf(tau[(bi & 7) * 8 + j]);
  return (sE / (ta + 1e-8f)) / (1.f + expf(-(sE - ta) / tv));
}

// ---------------- D1. global max |x| -> per-block maxima ----------------
__global__ void k_maxabs(const float4* __restrict__ x, float* __restrict__ maxp, int n4) {
  __shared__ float red[4];
  int tid = blockIdx.x * 256 + threadIdx.x;
  float m = 0.f;
  for (int i = tid; i < n4; i += gridDim.x * 256) {
    float4 v = x[i];
    m = fmaxf(m, fmaxf(fmaxf(fabsf(v.x), fabsf(v.y)), fmaxf(fabsf(v.z), fabsf(v.w))));
  }
  m = wave_max(m);
  if ((threadIdx.x & 63) == 0) red[threadIdx.x >> 6] = m;
  __syncthreads();
  if (threadIdx.x == 0)
    maxp[blockIdx.x] = fmaxf(fmaxf(red[0], red[1]), fmaxf(red[2], red[3]));
}

// ---------------- D2. spline ONCE (float4-vectorized): act + energies ---
__global__ void k_spline(const float4* __restrict__ x4, const float* __restrict__ sw,
                         const float* __restrict__ omiga, const float* __restrict__ maxp,
                         float4* __restrict__ act4, float* __restrict__ esum_p) {
  int tile = blockIdx.x, bi = blockIdx.y;
  int i = bi & 7;
  __shared__ float wl[J_N * C_N];
  __shared__ float aom[J_N];
  __shared__ float red[4 * J_N];
  for (int t = threadIdx.x; t < J_N * C_N; t += 256) wl[t] = sw[i * J_N * C_N + t];
  if (threadIdx.x < J_N) aom[threadIdx.x] = fabsf(omiga[i * J_N + threadIdx.x]);
  int lane = threadIdx.x & 63, wid = threadIdx.x >> 6;
  float inv = get_inv095(maxp);
  __syncthreads();
  int i4 = tile * 256 + threadIdx.x;
  float e[J_N] = {0, 0, 0, 0, 0, 0, 0, 0};
  if (i4 < SF4_N) {
    float4 xv = x4[(long)bi * SF4_N + i4];
    float xs[4] = {xv.x, xv.y, xv.z, xv.w};
    float4 av[J_N];
#pragma unroll
    for (int c = 0; c < 4; c++) {
      float x = xs[c];
      float xn = fminf(fmaxf(x * inv, -0.99f), 0.99f);
      float u = (xn + 1.f) * 33.f;
      int c0 = (int)floorf(u) - 1;
      float sm[J_N] = {0, 0, 0, 0, 0, 0, 0, 0};
#pragma unroll
      for (int kk = 0; kk < 4; kk++) {
        int cc = c0 + kk;
        if (cc >= 0 && cc < C_N) {
          float bas = bspline(fabsf(u - (float)cc));
#pragma unroll
          for (int j = 0; j < J_N; j++) sm[j] += bas * wl[j * C_N + cc];
        }
      }
#pragma unroll
      for (int j = 0; j < J_N; j++) {
        float a = sm[j] + aom[j] * x;
        (&av[j].x)[c] = a;
        e[j] += a * a;
      }
    }
#pragma unroll
    for (int j = 0; j < J_N; j++) act4[((long)(bi * 8 + j)) * SF4_N + i4] = av[j];
  }
#pragma unroll
  for (int j = 0; j < J_N; j++) {
    float v = e[j];
#pragma unroll
    for (int off = 32; off > 0; off >>= 1) v += __shfl_down(v, off, 64);
    if (lane == 0) red[wid * J_N + j] = v;
  }
  __syncthreads();
  if (threadIdx.x < J_N)
    esum_p[((long)bi * 8 + threadIdx.x) * NT_SPL + tile] =
        red[threadIdx.x] + red[8 + threadIdx.x] + red[16 + threadIdx.x] + red[24 + threadIdx.x];
}

// ---------------- D3. mid2 = combined(stream act) U ktqt16 --------------
// ktqt16: one block per (bj, 16-row fragment tile); fragments staged in LDS
// (cheap scatter) then written to global as full-line 16B/lane streaming
// stores. Was: 8-byte global scatter with each 64B line shared by 8 waves
// across blocks/XCDs -> write-allocate + coherence bounce on 25 MB.
__global__ void k_mid2(const float4* __restrict__ act4, const float* __restrict__ esum_p,
                       const float* __restrict__ tau, const float* __restrict__ temp,
                       const float* __restrict__ proj, float4* __restrict__ comb4,
                       _Float16* __restrict__ khi, _Float16* __restrict__ klo,
                       _Float16* __restrict__ qhi, _Float16* __restrict__ qlo) {
  __shared__ _Float16 stg[4][4096];   // 32 KB frag staging (ktqt16 branch)
  __shared__ float mk[64];
  int lane = threadIdx.x & 63;
  if (blockIdx.x < NCOMB) {
    // ---- combined: float4 masked streaming sum over act ----
    int b = blockIdx.x / NT_SPL, tile = blockIdx.x - b * NT_SPL;
    if (threadIdx.x < 64) {
      int i = threadIdx.x >> 3, j = threadIdx.x & 7;
      const float* p = esum_p + ((long)(b * 8 + i) * 8 + j) * NT_SPL;
      float s = 0.f;
#pragma unroll
      for (int k = 0; k < NT_SPL; k++) s += p[k];
      float sE = sqrtf(s * (1.f / (float)SF_N) + 1e-8f);
      float ta = fabsf(tau[i * 8 + j]);
      float tv = fabsf(temp[0]) * SQRT_SF + 1e-4f;
      mk[threadIdx.x] = 1.f / (1.f + expf(-(sE - ta) / tv));
    }
    __syncthreads();
    int i4 = tile * 256 + threadIdx.x;
    if (i4 < SF4_N) {
      float4 cb[J_N] = {};
#pragma unroll
      for (int i = 0; i < IN_N; i++) {
#pragma unroll
        for (int j = 0; j < J_N; j++) {
          float4 a = act4[((long)((b * 8 + i) * 8 + j)) * SF4_N + i4];
          float g = mk[i * 8 + j];
          cb[j].x += g * a.x; cb[j].y += g * a.y;
          cb[j].z += g * a.z; cb[j].w += g * a.w;
        }
      }
#pragma unroll
      for (int j = 0; j < J_N; j++) comb4[((long)(b * J_N + j)) * SF4_N + i4] = cb[j];
    }
  } else {
    // ---- ktqt16: block = (bj, stile); wave w rows stile*16 + w*4 .. +3 ----
    int blk = blockIdx.x - NCOMB;           // 0..767
    int bj = blk / 12, stile = blk - bj * 12;
    int b = bj >> 3, j = bj & 7;
    int w = threadIdx.x >> 6;
    int ig = lane >> 4;                     // i-group 0..3
    int f4 = (lane & 15) * 4;               // f base
    int iK = b * 8 + 2 * ig, iQ = iK + 1;
    float tv = fabsf(temp[0]) * SQRT_SF + 1e-4f;
    float gK = gate_g(esum_p, iK, j, tau, tv);
    float gQ = gate_g(esum_p, iQ, j, tau, tv);
    // lane's fragment slot within a 4096-half tile (m16 filled per row)
    int slotbase = (lane >> 3) * 512 + ((lane >> 1) & 3) * 128 + (lane & 1) * 4;
    for (int rr = 0; rr < 4; rr++) {
      int m16 = w * 4 + rr;
      int s = stile * 16 + m16;
      half4 hk4 = {}, lk4 = {}, hq4 = {}, lq4 = {};
      if (s < S_N) {
        float4 kr = *(const float4*)(proj + ((long)iK * S_N + s) * 64 + f4);
        float4 qr = *(const float4*)(proj + ((long)iQ * S_N + s) * 64 + f4);
        float kv[4] = {kr.x * gK, kr.y * gK, kr.z * gK, kr.w * gK};
        float qv[4] = {qr.x * gQ, qr.y * gQ, qr.z * gQ, qr.w * gQ};
        float mkv = wave_sum(kv[0] + kv[1] + kv[2] + kv[3]) * (1.f / 256.f);
        float mqv = wave_sum(qv[0] + qv[1] + qv[2] + qv[3]) * (1.f / 256.f);
        float vk = 0.f, vq = 0.f;
#pragma unroll
        for (int q = 0; q < 4; q++) {
          float dk = kv[q] - mkv; vk += dk * dk;
          float dq = qv[q] - mqv; vq += dq * dq;
        }
        vk = wave_sum(vk) * (1.f / 256.f);
        vq = wave_sum(vq) * (1.f / 256.f);
        float ik = 1.f / sqrtf(vk + 1e-5f);
        float iq = 1.f / sqrtf(vq + 1e-5f);
#pragma unroll
        for (int q = 0; q < 4; q++) {
          float fk = (kv[q] - mkv) * ik;
          float fq = (qv[q] - mqv) * iq;
          _Float16 hk = (_Float16)fk;
          _Float16 hq = (_Float16)fq;
          hk4[q] = hk; lk4[q] = (_Float16)(fk - (float)hk);
          hq4[q] = hq; lq4[q] = (_Float16)(fq - (float)hq);
        }
      }
      int off = slotbase + m16 * 8;
      *(half4*)&stg[0][off] = hk4;
      *(half4*)&stg[1][off] = lk4;
      *(half4*)&stg[2][off] = hq4;
      *(half4*)&stg[3][off] = lq4;
    }
    __syncthreads();
    // streamed write-out: 4096 halves per array = 512 float4; 2 per thread
    long gb = ((long)bj * 12 + stile) * 4096;
    float4* dk = (float4*)(khi + gb);
    float4* dkl = (float4*)(klo + gb);
    float4* dq = (float4*)(qhi + gb);
    float4* dql = (float4*)(qlo + gb);
    const float4* s0 = (const float4*)stg[0];
    const float4* s1 = (const float4*)stg[1];
    const float4* s2 = (const float4*)stg[2];
    const float4* s3 = (const float4*)stg[3];
    int t = threadIdx.x;
    dk[t] = s0[t];  dk[t + 256] = s0[t + 256];
    dkl[t] = s1[t]; dkl[t + 256] = s1[t + 256];
    dq[t] = s2[t];  dq[t + 256] = s2[t + 256];
    dql[t] = s3[t]; dql[t + 256] = s3[t + 256];
  }
}

// ---------------- D4. xprime: LN(comb)*W2 + bparam ----------------------
__global__ void k_xp(const float* __restrict__ comb, const float* __restrict__ W2,
                     const float* __restrict__ bparam, const float* __restrict__ lns,
                     const float* __restrict__ lnb, float* __restrict__ xprime) {
  __shared__ float smem[64 * 64 + 128];
  int lane = threadIdx.x & 63;
  int tile = blockIdx.x % 12, bj = blockIdx.x / 12;
  int j = bj & 7;
  float* w2s = smem;
  float* lss = smem + 4096;
  float* lbs = smem + 4160;
  const float4* wg = (const float4*)(W2 + j * 4096);
  float4* ws4 = (float4*)w2s;
  for (int idx = threadIdx.x; idx < 1024; idx += 256) ws4[idx] = wg[idx];
  if (threadIdx.x < 64) {
    lss[threadIdx.x] = lns[j * 64 + threadIdx.x];
    lbs[threadIdx.x] = lnb[j * 64 + threadIdx.x];
  }
  __syncthreads();
  int w = threadIdx.x >> 6;
  int sbase = tile * 16 + w * 4;
  float xln[4], acc[4];
#pragma unroll
  for (int rr = 0; rr < 4; rr++) {
    int s = sbase + rr;
    int sc = (s < S_N) ? s : S_N - 1;
    float x = comb[((long)bj * S_N + sc) * 64 + lane];
    float m = wave_sum(x) * (1.f / 64.f);
    float d = x - m;
    float var = wave_sum(d * d) * (1.f / 64.f);
    xln[rr] = d / sqrtf(var + 1e-5f) * lss[lane] + lbs[lane];
    acc[rr] = bparam[(j * S_N + sc) * 64 + lane];
  }
#pragma unroll
  for (int h = 0; h < 64; h++) {
    float w2v = w2s[h * 64 + lane];
#pragma unroll
    for (int rr = 0; rr < 4; rr++) acc[rr] += lane_bc(xln[rr], h) * w2v;
  }
#pragma unroll
  for (int rr = 0; rr < 4; rr++) {
    int s = sbase + rr;
    if (s < S_N) xprime[((long)bj * S_N + s) * 64 + lane] = acc[rr];
  }
}

// ---------------- D5. rawfinal: MFMA -> LDS w1 -> softmax -> apply ------
// grid (4 chunks of 48 rows, 64 bj), 256 thr. w1 never touches global:
// each block computes its 48x187 score chunk straight into 36 KB LDS,
// softmaxes in place, then applies attn + conv + residuals.
__global__ void k_rawfinal(const _Float16* __restrict__ khi, const _Float16* __restrict__ klo,
                           const _Float16* __restrict__ qhi, const _Float16* __restrict__ qlo,
                           const float* __restrict__ temp, const float* __restrict__ xprime,
                           const float* __restrict__ comb, const float* __restrict__ w3,
                           const float* __restrict__ alpha, const float* __restrict__ beta,
                           const float* __restrict__ theta, const float* __restrict__ gamma,
                           float* __restrict__ out) {
  __shared__ float w1t[48 * 188];    // 36096 B
  int chunk = blockIdx.x, bj = blockIdx.y;
  int j = bj & 7;
  int w = threadIdx.x >> 6, lane = threadIdx.x & 63;
  int quad = lane >> 4, m16 = lane & 15;
  long fb = (long)bj * FRAG_BJ + lane * 8;
  // ---- MFMA: wave w owns tt = 3w..3w+2 for all 3 ts of this chunk ----
  floatx4 acc[3][3] = {};
#pragma unroll
  for (int ts = 0; ts < 3; ts++) {
    const _Float16* ah_p = khi + fb + (long)(chunk * 3 + ts) * 4096;
    const _Float16* al_p = klo + fb + (long)(chunk * 3 + ts) * 4096;
    for (int ec = 0; ec < 8; ec++) {
      half8 ah = *(const half8*)(ah_p + ec * 512);
      half8 al = *(const half8*)(al_p + ec * 512);
#pragma unroll
      for (int n = 0; n < 3; n++) {
        long bo = fb + (long)(w * 3 + n) * 4096 + ec * 512;
        half8 bh = *(const half8*)(qhi + bo);
        half8 bl = *(const half8*)(qlo + bo);
        acc[ts][n] = __builtin_amdgcn_mfma_f32_16x16x32_f16(ah, bh, acc[ts][n], 0, 0, 0);
        acc[ts][n] = __builtin_amdgcn_mfma_f32_16x16x32_f16(al, bh, acc[ts][n], 0, 0, 0);
        acc[ts][n] = __builtin_amdgcn_mfma_f32_16x16x32_f16(ah, bl, acc[ts][n], 0, 0, 0);
      }
    }
  }
  float tv = fabsf(temp[0]) * SQRT_SF + 1e-4f;
  float scale = 1.f / (16.f * tv);
#pragma unroll
  for (int ts = 0; ts < 3; ts++)
#pragma unroll
    for (int n = 0; n < 3; n++) {
      int t = (w * 3 + n) * 16 + m16;  // 0..191
      if (t >= S_N) continue;
#pragma unroll
      for (int r = 0; r < 4; r++)
        w1t[(ts * 16 + quad * 4 + r) * 188 + t] = acc[ts][n][r] * scale;
    }
  __syncthreads();
  // ---- softmax on this wave's 12 rows ----
  int o = lane;
#pragma unroll
  for (int rr = 0; rr < 12; rr++) {
    int rl = w * 12 + rr;
    if (chunk * 48 + rl >= S_N) continue;
    float* row = &w1t[rl * 188];
    float v[3];
    float m = -1e30f;
#pragma unroll
    for (int q = 0; q < 3; q++) {
      int t = o + q * 64;
      v[q] = (t < S_N) ? row[t] : -1e30f;
      m = fmaxf(m, v[q]);
    }
    m = wave_max(m);
    float ssum = 0.f;
#pragma unroll
    for (int q = 0; q < 3; q++) {
      int t = o + q * 64;
      float e = (t < S_N) ? expf(v[q] - m) : 0.f;
      v[q] = e;
      ssum += e;
    }
    ssum = wave_sum(ssum);
    float invs = 1.f / ssum;
#pragma unroll
    for (int q = 0; q < 3; q++) {
      int t = o + q * 64;
      if (t < S_N) row[t] = v[q] * invs;
    }
  }
  __syncthreads();
  // ---- apply + conv + residuals on the same 12 rows (3 groups of 4) ----
  float w3c[KS_N];
#pragma unroll
  for (int k = 0; k < KS_N; k++) w3c[k] = w3[j * 64 * KS_N + o * KS_N + k];
  const float* xpg = xprime + (long)bj * (S_N * 64);
  float aa = fabsf(alpha[j]), ba = fabsf(beta[j]), ta = fabsf(theta[j]), gv = gamma[j];
  for (int g = 0; g < 3; g++) {
    int rbase = w * 12 + g * 4;
    float acc2[4] = {0.f, 0.f, 0.f, 0.f};
    for (int t = 0; t < 184; t += 4) {
      float x0 = xpg[t * 64 + o];
      float x1 = xpg[(t + 1) * 64 + o];
      float x2 = xpg[(t + 2) * 64 + o];
      float x3 = xpg[(t + 3) * 64 + o];
#pragma unroll
      for (int rr = 0; rr < 4; rr++) {
        float4 wv = *(const float4*)&w1t[(rbase + rr) * 188 + t];
        acc2[rr] += wv.x * x0 + wv.y * x1 + wv.z * x2 + wv.w * x3;
      }
    }
#pragma unroll
    for (int t = 184; t < S_N; t++) {
      float xv = xpg[t * 64 + o];
#pragma unroll
      for (int rr = 0; rr < 4; rr++) acc2[rr] += w1t[(rbase + rr) * 188 + t] * xv;
    }
#pragma unroll
    for (int rr = 0; rr < 4; rr++) {
      int s = chunk * 48 + rbase + rr;
      if (s >= S_N) continue;
      float conv = 0.f;
#pragma unroll
      for (int k = 0; k < KS_N; k++) {
        int si = s + k - 7;
        if (si >= 0 && si < S_N) conv += xpg[si * 64 + o] * w3c[k];
      }
      float res = ba * acc2[rr] + aa * xpg[s * 64 + o] + ta * conv +
                  gv * comb[((long)bj * S_N + s) * 64 + o];
      out[((long)bj * S_N + s) * 64 + o] = res;
    }
  }
}

extern "C" void kernel_launch(void* const* d_in, const int* in_sizes, int n_in,
                              void* d_out, int out_size, void* d_ws, size_t ws_size,
                              hipStream_t stream) {
  const float* x_in   = (const float*)d_in[0];
  const float* proj   = (const float*)d_in[1];
  const float* sw     = (const float*)d_in[2];
  const float* tau    = (const float*)d_in[3];
  const float* temp   = (const float*)d_in[4];
  const float* omiga  = (const float*)d_in[5];
  const float* W2     = (const float*)d_in[6];
  const float* bparam = (const float*)d_in[7];
  const float* lns    = (const float*)d_in[8];
  const float* lnb    = (const float*)d_in[9];
  const float* alpha  = (const float*)d_in[10];
  const float* beta   = (const float*)d_in[11];
  const float* theta  = (const float*)d_in[12];
  const float* gamma  = (const float*)d_in[13];
  const float* w3     = (const float*)d_in[14];

  float* out = (float*)d_out;
  float* xprime = out + B_N * J_N * S_N * O_N;  // second output, written directly

  float* wsf = (float*)d_ws;
  float* maxp   = wsf;                            // 256 floats
  float* esum_p = wsf + 512;                      // 512*12 floats
  float* act    = wsf + 512 + 512 * NT_SPL;       // 64*8*SF_N floats = 24.5 MB
  const long ACT_N = (long)64 * 8 * SF_N;
  const long FR = (long)64 * FRAG_BJ;             // 3,145,728 halves per frag array
  _Float16* khi = (_Float16*)(act + ACT_N);
  _Float16* klo = khi + FR;
  _Float16* qhi = klo + FR;
  _Float16* qlo = qhi + FR;
  float* comb = (float*)(qlo + FR);

  k_maxabs<<<NMAXP, 256, 0, stream>>>((const float4*)x_in, maxp, (B_N * IN_N * S_N * F_N) / 4);
  k_spline<<<dim3(NT_SPL, 64), 256, 0, stream>>>((const float4*)x_in, sw, omiga, maxp,
                                                 (float4*)act, esum_p);
  k_mid2<<<NCOMB + NKT16, 256, 0, stream>>>((const float4*)act, esum_p, tau, temp,
                                            proj, (float4*)comb, khi, klo, qhi, qlo);
  k_xp<<<NXPR, 256, 0, stream>>>(comb, W2, bparam, lns, lnb, xprime);
  k_rawfinal<<<dim3(4, 64), 256, 0, stream>>>(khi, klo, qhi, qlo, temp, xprime, comb,
                                              w3, alpha, beta, theta, gamma, out);
}

// Round 5
// 165.553 us; speedup vs baseline: 1.0957x; 1.0957x over previous
//
#include <hip/hip_runtime.h>
#include <math.h>

#define B_N 8
#define IN_N 8
#define J_N 8
#define S_N 187
#define F_N 64
#define O_N 64
#define C_N 67
#define KS_N 15
#define SF_N (S_N * F_N)   // 11968
#define SF4_N (SF_N / 4)   // 2992 float4s per (b,i) plane
#define SQRT_SF 0.85467470f  // sqrt(187/256)

#define NT_SPL 12           // 1024-wide idx tiles (256 float4/block) covering SF_N
#define NCOMB 384           // combined blocks (8 b * 4 jg * 12 tiles)
#define NKT16 768           // ktqt16 blocks (64 bj * 12 stiles)
#define NRAW 576            // raw blocks in k_gemm (3*3*64)
#define NXPR 768            // xprime blocks in k_gemm (12*64)
#define NMAXP 256           // maxabs partial blocks
#define FRAG_BJ 49152       // 12 stiles * 4096 halves per bj

typedef __attribute__((ext_vector_type(8))) _Float16 half8;
typedef __attribute__((ext_vector_type(4))) _Float16 half4;
typedef __attribute__((ext_vector_type(4))) float floatx4;

// ---------------- wave helpers (wave = 64) ----------------
__device__ __forceinline__ float wave_sum(float v) {
#pragma unroll
  for (int off = 32; off > 0; off >>= 1) v += __shfl_down(v, off, 64);
  return __shfl(v, 0, 64);
}
__device__ __forceinline__ float wave_max(float v) {
#pragma unroll
  for (int off = 32; off > 0; off >>= 1) v = fmaxf(v, __shfl_down(v, off, 64));
  return __shfl(v, 0, 64);
}
__device__ __forceinline__ float lane_bc(float v, int l) {
  return __int_as_float(__builtin_amdgcn_readlane(__float_as_int(v), l));
}
__device__ __forceinline__ float bspline(float d) {
  float t2 = fmaxf(2.f - d, 0.f);
  float t1 = fmaxf(1.f - d, 0.f);
  return t2 * t2 * t2 * (1.f / 6.f) - t1 * t1 * t1 * (4.f / 6.f);
}
__device__ __forceinline__ float get_inv095(const float* __restrict__ maxp) {
  int lane = threadIdx.x & 63;
  float m = 0.f;
#pragma unroll
  for (int k = 0; k < NMAXP / 64; k++) m = fmaxf(m, maxp[lane + k * 64]);
  return 0.95f / (wave_max(m) + 1e-8f);
}
// gate = (sqrtE/tau) * sigmoid((sqrtE-tau)/tv) from the 12 per-tile partials
__device__ __forceinline__ float gate_g(const float* __restrict__ esum_p, int bi, int j,
                                        const float* __restrict__ tau, float tv) {
  const float* p = esum_p + ((long)bi * 8 + j) * NT_SPL;
  float s = 0.f;
#pragma unroll
  for (int k = 0; k < NT_SPL; k++) s += p[k];
  float sE = sqrtf(s * (1.f / (float)SF_N) + 1e-8f);
  float ta = fabsf(tau[(bi & 7) * 8 + j]);
  return (sE / (ta + 1e-8f)) / (1.f + expf(-(sE - ta) / tv));
}

// ---------------- D1. global max |x| -> per-block maxima ----------------
__global__ void k_maxabs(const float4* __restrict__ x, float* __restrict__ maxp, int n4) {
  __shared__ float red[4];
  int tid = blockIdx.x * 256 + threadIdx.x;
  float m = 0.f;
  for (int i = tid; i < n4; i += gridDim.x * 256) {
    float4 v = x[i];
    m = fmaxf(m, fmaxf(fmaxf(fabsf(v.x), fabsf(v.y)), fmaxf(fabsf(v.z), fabsf(v.w))));
  }
  m = wave_max(m);
  if ((threadIdx.x & 63) == 0) red[threadIdx.x >> 6] = m;
  __syncthreads();
  if (threadIdx.x == 0)
    maxp[blockIdx.x] = fmaxf(fmaxf(red[0], red[1]), fmaxf(red[2], red[3]));
}

// ---------------- D2. spline ONCE (float4-vectorized): act + energies ---
__global__ void k_spline(const float4* __restrict__ x4, const float* __restrict__ sw,
                         const float* __restrict__ omiga, const float* __restrict__ maxp,
                         float4* __restrict__ act4, float* __restrict__ esum_p) {
  int tile = blockIdx.x, bi = blockIdx.y;
  int i = bi & 7;
  __shared__ float wl[J_N * C_N];
  __shared__ float aom[J_N];
  __shared__ float red[4 * J_N];
  for (int t = threadIdx.x; t < J_N * C_N; t += 256) wl[t] = sw[i * J_N * C_N + t];
  if (threadIdx.x < J_N) aom[threadIdx.x] = fabsf(omiga[i * J_N + threadIdx.x]);
  int lane = threadIdx.x & 63, wid = threadIdx.x >> 6;
  float inv = get_inv095(maxp);
  __syncthreads();
  int i4 = tile * 256 + threadIdx.x;
  float e[J_N] = {0, 0, 0, 0, 0, 0, 0, 0};
  if (i4 < SF4_N) {
    float4 xv = x4[(long)bi * SF4_N + i4];
    float xs[4] = {xv.x, xv.y, xv.z, xv.w};
    float4 av[J_N];
#pragma unroll
    for (int c = 0; c < 4; c++) {
      float x = xs[c];
      float xn = fminf(fmaxf(x * inv, -0.99f), 0.99f);
      float u = (xn + 1.f) * 33.f;
      int c0 = (int)floorf(u) - 1;
      float sm[J_N] = {0, 0, 0, 0, 0, 0, 0, 0};
#pragma unroll
      for (int kk = 0; kk < 4; kk++) {
        int cc = c0 + kk;
        if (cc >= 0 && cc < C_N) {
          float bas = bspline(fabsf(u - (float)cc));
#pragma unroll
          for (int j = 0; j < J_N; j++) sm[j] += bas * wl[j * C_N + cc];
        }
      }
#pragma unroll
      for (int j = 0; j < J_N; j++) {
        float a = sm[j] + aom[j] * x;
        (&av[j].x)[c] = a;
        e[j] += a * a;
      }
    }
#pragma unroll
    for (int j = 0; j < J_N; j++) act4[((long)(bi * 8 + j)) * SF4_N + i4] = av[j];
  }
#pragma unroll
  for (int j = 0; j < J_N; j++) {
    float v = e[j];
#pragma unroll
    for (int off = 32; off > 0; off >>= 1) v += __shfl_down(v, off, 64);
    if (lane == 0) red[wid * J_N + j] = v;
  }
  __syncthreads();
  if (threadIdx.x < J_N)
    esum_p[((long)bi * 8 + threadIdx.x) * NT_SPL + tile] =
        red[threadIdx.x] + red[8 + threadIdx.x] + red[16 + threadIdx.x] + red[24 + threadIdx.x];
}

// ---------------- D3. mid2 = combined (j-split x4) U ktqt16 -------------
// combined: 384 blocks (was 96 = 0.37 blocks/CU, 5/8 of chip idle). The
// j-range is split 4 ways: each block reads only its own 16 (i,j)-planes,
// so the split adds zero extra traffic.
// ktqt16: fragments staged in LDS then written as full-line 16B/lane
// streaming stores (R4); layout verified against k_gemm's lane*8 reads.
__global__ void k_mid2(const float4* __restrict__ act4, const float* __restrict__ esum_p,
                       const float* __restrict__ tau, const float* __restrict__ temp,
                       const float* __restrict__ proj, float4* __restrict__ comb4,
                       _Float16* __restrict__ khi, _Float16* __restrict__ klo,
                       _Float16* __restrict__ qhi, _Float16* __restrict__ qlo) {
  __shared__ _Float16 stg[4][4096];   // 32 KB frag staging (ktqt16 branch)
  __shared__ float mk[16];
  int lane = threadIdx.x & 63;
  if (blockIdx.x < NCOMB) {
    // ---- combined: blk = (b*4 + jg)*12 + tile; j in {jg*2, jg*2+1} ----
    int blk = blockIdx.x;
    int tile = blk % 12, bjg = blk / 12;
    int jg = bjg & 3, b = bjg >> 2;
    int j0 = jg * 2;
    if (threadIdx.x < 16) {
      int i = threadIdx.x >> 1, j = j0 + (threadIdx.x & 1);
      const float* p = esum_p + ((long)(b * 8 + i) * 8 + j) * NT_SPL;
      float s = 0.f;
#pragma unroll
      for (int k = 0; k < NT_SPL; k++) s += p[k];
      float sE = sqrtf(s * (1.f / (float)SF_N) + 1e-8f);
      float ta = fabsf(tau[i * 8 + j]);
      float tv = fabsf(temp[0]) * SQRT_SF + 1e-4f;
      mk[threadIdx.x] = 1.f / (1.f + expf(-(sE - ta) / tv));
    }
    __syncthreads();
    int i4 = tile * 256 + threadIdx.x;
    if (i4 < SF4_N) {
      float4 cb[2] = {};
#pragma unroll
      for (int i = 0; i < IN_N; i++) {
#pragma unroll
        for (int jj = 0; jj < 2; jj++) {
          float4 a = act4[((long)((b * 8 + i) * 8 + j0 + jj)) * SF4_N + i4];
          float g = mk[i * 2 + jj];
          cb[jj].x += g * a.x; cb[jj].y += g * a.y;
          cb[jj].z += g * a.z; cb[jj].w += g * a.w;
        }
      }
#pragma unroll
      for (int jj = 0; jj < 2; jj++)
        comb4[((long)(b * J_N + j0 + jj)) * SF4_N + i4] = cb[jj];
    }
  } else {
    // ---- ktqt16: block = (bj, stile); wave w rows stile*16 + w*4 .. +3 ----
    int blk = blockIdx.x - NCOMB;           // 0..767
    int bj = blk / 12, stile = blk - bj * 12;
    int b = bj >> 3, j = bj & 7;
    int w = threadIdx.x >> 6;
    int ig = lane >> 4;                     // i-group 0..3
    int f4 = (lane & 15) * 4;               // f base
    int iK = b * 8 + 2 * ig, iQ = iK + 1;
    float tv = fabsf(temp[0]) * SQRT_SF + 1e-4f;
    float gK = gate_g(esum_p, iK, j, tau, tv);
    float gQ = gate_g(esum_p, iQ, j, tau, tv);
    // lane's fragment slot within a 4096-half tile (m16 filled per row)
    int slotbase = (lane >> 3) * 512 + ((lane >> 1) & 3) * 128 + (lane & 1) * 4;
    for (int rr = 0; rr < 4; rr++) {
      int m16 = w * 4 + rr;
      int s = stile * 16 + m16;
      half4 hk4 = {}, lk4 = {}, hq4 = {}, lq4 = {};
      if (s < S_N) {
        float4 kr = *(const float4*)(proj + ((long)iK * S_N + s) * 64 + f4);
        float4 qr = *(const float4*)(proj + ((long)iQ * S_N + s) * 64 + f4);
        float kv[4] = {kr.x * gK, kr.y * gK, kr.z * gK, kr.w * gK};
        float qv[4] = {qr.x * gQ, qr.y * gQ, qr.z * gQ, qr.w * gQ};
        float mkv = wave_sum(kv[0] + kv[1] + kv[2] + kv[3]) * (1.f / 256.f);
        float mqv = wave_sum(qv[0] + qv[1] + qv[2] + qv[3]) * (1.f / 256.f);
        float vk = 0.f, vq = 0.f;
#pragma unroll
        for (int q = 0; q < 4; q++) {
          float dk = kv[q] - mkv; vk += dk * dk;
          float dq = qv[q] - mqv; vq += dq * dq;
        }
        vk = wave_sum(vk) * (1.f / 256.f);
        vq = wave_sum(vq) * (1.f / 256.f);
        float ik = 1.f / sqrtf(vk + 1e-5f);
        float iq = 1.f / sqrtf(vq + 1e-5f);
#pragma unroll
        for (int q = 0; q < 4; q++) {
          float fk = (kv[q] - mkv) * ik;
          float fq = (qv[q] - mqv) * iq;
          _Float16 hk = (_Float16)fk;
          _Float16 hq = (_Float16)fq;
          hk4[q] = hk; lk4[q] = (_Float16)(fk - (float)hk);
          hq4[q] = hq; lq4[q] = (_Float16)(fq - (float)hq);
        }
      }
      int off = slotbase + m16 * 8;
      *(half4*)&stg[0][off] = hk4;
      *(half4*)&stg[1][off] = lk4;
      *(half4*)&stg[2][off] = hq4;
      *(half4*)&stg[3][off] = lq4;
    }
    __syncthreads();
    // streamed write-out: 4096 halves per array = 512 float4; 2 per thread
    long gb = ((long)bj * 12 + stile) * 4096;
    float4* dk = (float4*)(khi + gb);
    float4* dkl = (float4*)(klo + gb);
    float4* dq = (float4*)(qhi + gb);
    float4* dql = (float4*)(qlo + gb);
    const float4* s0 = (const float4*)stg[0];
    const float4* s1 = (const float4*)stg[1];
    const float4* s2 = (const float4*)stg[2];
    const float4* s3 = (const float4*)stg[3];
    int t = threadIdx.x;
    dk[t] = s0[t];  dk[t + 256] = s0[t + 256];
    dkl[t] = s1[t]; dkl[t + 256] = s1[t + 256];
    dq[t] = s2[t];  dq[t + 256] = s2[t + 256];
    dql[t] = s3[t]; dql[t + 256] = s3[t + 256];
  }
}

// ---------------- D4. gemm = raw (MFMA, coalesced frags) U xprime -------
// Un-fused from R4's k_rawfinal: 1344 blocks restores occupancy (R4 fusion
// was 256 blocks = 1/CU = 9.5% occupancy, 68 us; raw+xp+final as separate
// wide launches stay under the fill noise floor).
__global__ void k_gemm(const _Float16* __restrict__ khi, const _Float16* __restrict__ klo,
                       const _Float16* __restrict__ qhi, const _Float16* __restrict__ qlo,
                       const float* __restrict__ temp, float* __restrict__ w1,
                       const float* __restrict__ comb, const float* __restrict__ W2,
                       const float* __restrict__ bparam, const float* __restrict__ lns,
                       const float* __restrict__ lnb, float* __restrict__ xprime) {
  __shared__ float smem[64 * 64 + 128];
  int lane = threadIdx.x & 63;
  if (blockIdx.x < NRAW) {
    // ---- raw: idx = st + 3*tt + 9*bj; operands read in fragment order ----
    int idx = blockIdx.x;
    int st = idx % 3, tt = (idx / 3) % 3, bj = idx / 9;
    int wave = threadIdx.x >> 6;
    int quad = lane >> 4, m16 = lane & 15;
    long fb = (long)bj * FRAG_BJ + lane * 8;
    const _Float16* ah_p = khi + fb + (st * 4 + wave) * 4096;
    const _Float16* al_p = klo + fb + (st * 4 + wave) * 4096;
    const _Float16* bh_p = qhi + fb + tt * 4 * 4096;
    const _Float16* bl_p = qlo + fb + tt * 4 * 4096;
    floatx4 acc[4] = {};
    for (int ec = 0; ec < 8; ec++) {
      half8 ah = *(const half8*)(ah_p + ec * 512);
      half8 al = *(const half8*)(al_p + ec * 512);
#pragma unroll
      for (int n = 0; n < 4; n++) {
        half8 bh = *(const half8*)(bh_p + n * 4096 + ec * 512);
        half8 bl = *(const half8*)(bl_p + n * 4096 + ec * 512);
        acc[n] = __builtin_amdgcn_mfma_f32_16x16x32_f16(ah, bh, acc[n], 0, 0, 0);
        acc[n] = __builtin_amdgcn_mfma_f32_16x16x32_f16(al, bh, acc[n], 0, 0, 0);
        acc[n] = __builtin_amdgcn_mfma_f32_16x16x32_f16(ah, bl, acc[n], 0, 0, 0);
      }
    }
    float tv = fabsf(temp[0]) * SQRT_SF + 1e-4f;
    float scale = 1.f / (16.f * tv);
#pragma unroll
    for (int n = 0; n < 4; n++) {
      int t = tt * 64 + n * 16 + m16;  // D col = lane&15
      if (t >= S_N) continue;
#pragma unroll
      for (int r = 0; r < 4; r++) {
        int s = st * 64 + wave * 16 + quad * 4 + r;  // D row = quad*4+reg
        if (s < S_N) w1[((long)bj * S_N + s) * S_N + t] = acc[n][r] * scale;
      }
    }
  } else {
    // ---- xprime: q = blk-576: tile = q%12, bj = q/12 ----
    int q = blockIdx.x - NRAW;
    int tile = q % 12, bj = q / 12;
    int j = bj & 7;
    float* w2s = smem;
    float* lss = smem + 4096;
    float* lbs = smem + 4160;
    const float4* wg = (const float4*)(W2 + j * 4096);
    float4* ws4 = (float4*)w2s;
    for (int idx = threadIdx.x; idx < 1024; idx += 256) ws4[idx] = wg[idx];
    if (threadIdx.x < 64) {
      lss[threadIdx.x] = lns[j * 64 + threadIdx.x];
      lbs[threadIdx.x] = lnb[j * 64 + threadIdx.x];
    }
    __syncthreads();
    int w = threadIdx.x >> 6;
    int sbase = tile * 16 + w * 4;
    float xln[4], acc[4];
#pragma unroll
    for (int rr = 0; rr < 4; rr++) {
      int s = sbase + rr;
      int sc = (s < S_N) ? s : S_N - 1;
      float x = comb[((long)bj * S_N + sc) * 64 + lane];
      float m = wave_sum(x) * (1.f / 64.f);
      float d = x - m;
      float var = wave_sum(d * d) * (1.f / 64.f);
      xln[rr] = d / sqrtf(var + 1e-5f) * lss[lane] + lbs[lane];
      acc[rr] = bparam[(j * S_N + sc) * 64 + lane];
    }
#pragma unroll
    for (int h = 0; h < 64; h++) {
      float w2v = w2s[h * 64 + lane];
#pragma unroll
      for (int rr = 0; rr < 4; rr++) acc[rr] += lane_bc(xln[rr], h) * w2v;
    }
#pragma unroll
    for (int rr = 0; rr < 4; rr++) {
      int s = sbase + rr;
      if (s < S_N) xprime[((long)bj * S_N + s) * 64 + lane] = acc[rr];
    }
  }
}

// ---------------- D5. final: softmax + attn apply + conv + residuals ----
// 768 blocks, 12 KB LDS -> 12 waves/CU; xp streams from global (L1/L2).
__global__ void k_final(const float* __restrict__ xprime, const float* __restrict__ w1,
                        const float* __restrict__ comb, const float* __restrict__ w3,
                        const float* __restrict__ alpha, const float* __restrict__ beta,
                        const float* __restrict__ theta, const float* __restrict__ gamma,
                        float* __restrict__ out) {
  int tile = blockIdx.x, bj = blockIdx.y;
  int j = bj & 7;
  __shared__ float w1t[16 * 188];    // 12032 B total LDS
  int s0 = tile * 16;
  for (int idx = threadIdx.x; idx < 16 * S_N; idx += 256) {
    int r = idx / S_N, t = idx - r * S_N;
    int srow = s0 + r;
    w1t[r * 188 + t] = (srow < S_N) ? w1[((long)bj * S_N + srow) * S_N + t] : 0.f;
  }
  __syncthreads();
  int w = threadIdx.x >> 6, o = threadIdx.x & 63;
  // in-LDS row softmax on this wave's 4 rows (consumed only by wave w)
#pragma unroll
  for (int rr = 0; rr < 4; rr++) {
    float* row = &w1t[(w * 4 + rr) * 188];
    float v[3];
    float m = -1e30f;
#pragma unroll
    for (int q = 0; q < 3; q++) {
      int t = o + q * 64;
      v[q] = (t < S_N) ? row[t] : -1e30f;
      m = fmaxf(m, v[q]);
    }
    m = wave_max(m);
    float ssum = 0.f;
#pragma unroll
    for (int q = 0; q < 3; q++) {
      int t = o + q * 64;
      float e = (t < S_N) ? expf(v[q] - m) : 0.f;
      v[q] = e;
      ssum += e;
    }
    ssum = wave_sum(ssum);
    float invs = 1.f / ssum;
#pragma unroll
    for (int q = 0; q < 3; q++) {
      int t = o + q * 64;
      if (t < S_N) row[t] = v[q] * invs;
    }
  }
  // conv taps straight from global (L1-resident: same j across the block)
  float w3c[KS_N];
#pragma unroll
  for (int k = 0; k < KS_N; k++) w3c[k] = w3[j * 64 * KS_N + o * KS_N + k];
  const float* xpg = xprime + (long)bj * (S_N * 64);
  float aa = fabsf(alpha[j]), ba = fabsf(beta[j]), ta = fabsf(theta[j]), gv = gamma[j];
  float acc[4] = {0.f, 0.f, 0.f, 0.f};
  for (int t = 0; t < 184; t += 4) {
    float x0 = xpg[t * 64 + o];
    float x1 = xpg[(t + 1) * 64 + o];
    float x2 = xpg[(t + 2) * 64 + o];
    float x3 = xpg[(t + 3) * 64 + o];
#pragma unroll
    for (int rr = 0; rr < 4; rr++) {
      float4 wv = *(const float4*)&w1t[(w * 4 + rr) * 188 + t];
      acc[rr] += wv.x * x0 + wv.y * x1 + wv.z * x2 + wv.w * x3;
    }
  }
#pragma unroll
  for (int t = 184; t < S_N; t++) {
    float xv = xpg[t * 64 + o];
#pragma unroll
    for (int rr = 0; rr < 4; rr++) acc[rr] += w1t[(w * 4 + rr) * 188 + t] * xv;
  }
#pragma unroll
  for (int rr = 0; rr < 4; rr++) {
    int s = s0 + w * 4 + rr;
    if (s >= S_N) continue;
    float conv = 0.f;
#pragma unroll
    for (int k = 0; k < KS_N; k++) {
      int si = s + k - 7;
      if (si >= 0 && si < S_N) conv += xpg[si * 64 + o] * w3c[k];
    }
    float res = ba * acc[rr] + aa * xpg[s * 64 + o] + ta * conv +
                gv * comb[((long)bj * S_N + s) * 64 + o];
    out[((long)bj * S_N + s) * 64 + o] = res;
  }
}

extern "C" void kernel_launch(void* const* d_in, const int* in_sizes, int n_in,
                              void* d_out, int out_size, void* d_ws, size_t ws_size,
                              hipStream_t stream) {
  const float* x_in   = (const float*)d_in[0];
  const float* proj   = (const float*)d_in[1];
  const float* sw     = (const float*)d_in[2];
  const float* tau    = (const float*)d_in[3];
  const float* temp   = (const float*)d_in[4];
  const float* omiga  = (const float*)d_in[5];
  const float* W2     = (const float*)d_in[6];
  const float* bparam = (const float*)d_in[7];
  const float* lns    = (const float*)d_in[8];
  const float* lnb    = (const float*)d_in[9];
  const float* alpha  = (const float*)d_in[10];
  const float* beta   = (const float*)d_in[11];
  const float* theta  = (const float*)d_in[12];
  const float* gamma  = (const float*)d_in[13];
  const float* w3     = (const float*)d_in[14];

  float* out = (float*)d_out;
  float* xprime = out + B_N * J_N * S_N * O_N;  // second output, written directly

  float* wsf = (float*)d_ws;
  float* maxp   = wsf;                            // 256 floats
  float* esum_p = wsf + 512;                      // 512*12 floats
  float* act    = wsf + 512 + 512 * NT_SPL;       // 64*8*SF_N floats = 24.5 MB
  const long ACT_N = (long)64 * 8 * SF_N;
  const long FR = (long)64 * FRAG_BJ;             // 3,145,728 halves per frag array
  _Float16* khi = (_Float16*)(act + ACT_N);
  _Float16* klo = khi + FR;
  _Float16* qhi = klo + FR;
  _Float16* qlo = qhi + FR;
  float* w1   = (float*)(qlo + FR);
  float* comb = w1 + (long)B_N * J_N * S_N * S_N;

  k_maxabs<<<NMAXP, 256, 0, stream>>>((const float4*)x_in, maxp, (B_N * IN_N * S_N * F_N) / 4);
  k_spline<<<dim3(NT_SPL, 64), 256, 0, stream>>>((const float4*)x_in, sw, omiga, maxp,
                                                 (float4*)act, esum_p);
  k_mid2<<<NCOMB + NKT16, 256, 0, stream>>>((const float4*)act, esum_p, tau, temp,
                                            proj, (float4*)comb, khi, klo, qhi, qlo);
  k_gemm<<<NRAW + NXPR, 256, 0, stream>>>(khi, klo, qhi, qlo, temp, w1,
                                          comb, W2, bparam, lns, lnb, xprime);
  k_final<<<dim3(12, 64), 256, 0, stream>>>(xprime, w1, comb, w3, alpha, beta, theta, gamma, out);
}

// Round 6
// 161.775 us; speedup vs baseline: 1.1213x; 1.0234x over previous
//
#include <hip/hip_runtime.h>
#include <math.h>

#define B_N 8
#define IN_N 8
#define J_N 8
#define S_N 187
#define F_N 64
#define O_N 64
#define C_N 67
#define KS_N 15
#define SF_N (S_N * F_N)   // 11968
#define SF4_N (SF_N / 4)   // 2992 float4s per (b,i) plane
#define SQRT_SF 0.85467470f  // sqrt(187/256)

#define NT_SPL 12           // 1024-wide idx tiles (256 float4/block) covering SF_N
#define NCOMB 384           // combined blocks (8 b * 4 jg * 12 tiles)
#define NKT16 768           // ktqt16 blocks (64 bj * 12 stiles)
#define NXPR 768            // xprime blocks (12*64)
#define NRF 768             // rawfinal blocks (64 bj * 12 stiles)
#define NMAXP 256           // maxabs partial blocks
#define FRAG_BJ 49152       // 12 stiles * 4096 halves per bj

typedef __attribute__((ext_vector_type(8))) _Float16 half8;
typedef __attribute__((ext_vector_type(4))) _Float16 half4;
typedef __attribute__((ext_vector_type(4))) float floatx4;

// ---------------- wave helpers (wave = 64) ----------------
__device__ __forceinline__ float wave_sum(float v) {
#pragma unroll
  for (int off = 32; off > 0; off >>= 1) v += __shfl_down(v, off, 64);
  return __shfl(v, 0, 64);
}
__device__ __forceinline__ float wave_max(float v) {
#pragma unroll
  for (int off = 32; off > 0; off >>= 1) v = fmaxf(v, __shfl_down(v, off, 64));
  return __shfl(v, 0, 64);
}
__device__ __forceinline__ float lane_bc(float v, int l) {
  return __int_as_float(__builtin_amdgcn_readlane(__float_as_int(v), l));
}
__device__ __forceinline__ float bspline(float d) {
  float t2 = fmaxf(2.f - d, 0.f);
  float t1 = fmaxf(1.f - d, 0.f);
  return t2 * t2 * t2 * (1.f / 6.f) - t1 * t1 * t1 * (4.f / 6.f);
}
__device__ __forceinline__ float get_inv095(const float* __restrict__ maxp) {
  int lane = threadIdx.x & 63;
  float m = 0.f;
#pragma unroll
  for (int k = 0; k < NMAXP / 64; k++) m = fmaxf(m, maxp[lane + k * 64]);
  return 0.95f / (wave_max(m) + 1e-8f);
}
// gate = (sqrtE/tau) * sigmoid((sqrtE-tau)/tv) from the 12 per-tile partials
__device__ __forceinline__ float gate_g(const float* __restrict__ esum_p, int bi, int j,
                                        const float* __restrict__ tau, float tv) {
  const float* p = esum_p + ((long)bi * 8 + j) * NT_SPL;
  float s = 0.f;
#pragma unroll
  for (int k = 0; k < NT_SPL; k++) s += p[k];
  float sE = sqrtf(s * (1.f / (float)SF_N) + 1e-8f);
  float ta = fabsf(tau[(bi & 7) * 8 + j]);
  return (sE / (ta + 1e-8f)) / (1.f + expf(-(sE - ta) / tv));
}

// ---------------- D1. global max |x| -> per-block maxima ----------------
__global__ void k_maxabs(const float4* __restrict__ x, float* __restrict__ maxp, int n4) {
  __shared__ float red[4];
  int tid = blockIdx.x * 256 + threadIdx.x;
  float m = 0.f;
  for (int i = tid; i < n4; i += gridDim.x * 256) {
    float4 v = x[i];
    m = fmaxf(m, fmaxf(fmaxf(fabsf(v.x), fabsf(v.y)), fmaxf(fabsf(v.z), fabsf(v.w))));
  }
  m = wave_max(m);
  if ((threadIdx.x & 63) == 0) red[threadIdx.x >> 6] = m;
  __syncthreads();
  if (threadIdx.x == 0)
    maxp[blockIdx.x] = fmaxf(fmaxf(red[0], red[1]), fmaxf(red[2], red[3]));
}

// ---------------- D2. spline ONCE (float4-vectorized): act + energies ---
__global__ void k_spline(const float4* __restrict__ x4, const float* __restrict__ sw,
                         const float* __restrict__ omiga, const float* __restrict__ maxp,
                         float4* __restrict__ act4, float* __restrict__ esum_p) {
  int tile = blockIdx.x, bi = blockIdx.y;
  int i = bi & 7;
  __shared__ float wl[J_N * C_N];
  __shared__ float aom[J_N];
  __shared__ float red[4 * J_N];
  for (int t = threadIdx.x; t < J_N * C_N; t += 256) wl[t] = sw[i * J_N * C_N + t];
  if (threadIdx.x < J_N) aom[threadIdx.x] = fabsf(omiga[i * J_N + threadIdx.x]);
  int lane = threadIdx.x & 63, wid = threadIdx.x >> 6;
  float inv = get_inv095(maxp);
  __syncthreads();
  int i4 = tile * 256 + threadIdx.x;
  float e[J_N] = {0, 0, 0, 0, 0, 0, 0, 0};
  if (i4 < SF4_N) {
    float4 xv = x4[(long)bi * SF4_N + i4];
    float xs[4] = {xv.x, xv.y, xv.z, xv.w};
    float4 av[J_N];
#pragma unroll
    for (int c = 0; c < 4; c++) {
      float x = xs[c];
      float xn = fminf(fmaxf(x * inv, -0.99f), 0.99f);
      float u = (xn + 1.f) * 33.f;
      int c0 = (int)floorf(u) - 1;
      float sm[J_N] = {0, 0, 0, 0, 0, 0, 0, 0};
#pragma unroll
      for (int kk = 0; kk < 4; kk++) {
        int cc = c0 + kk;
        if (cc >= 0 && cc < C_N) {
          float bas = bspline(fabsf(u - (float)cc));
#pragma unroll
          for (int j = 0; j < J_N; j++) sm[j] += bas * wl[j * C_N + cc];
        }
      }
#pragma unroll
      for (int j = 0; j < J_N; j++) {
        float a = sm[j] + aom[j] * x;
        (&av[j].x)[c] = a;
        e[j] += a * a;
      }
    }
#pragma unroll
    for (int j = 0; j < J_N; j++) act4[((long)(bi * 8 + j)) * SF4_N + i4] = av[j];
  }
#pragma unroll
  for (int j = 0; j < J_N; j++) {
    float v = e[j];
#pragma unroll
    for (int off = 32; off > 0; off >>= 1) v += __shfl_down(v, off, 64);
    if (lane == 0) red[wid * J_N + j] = v;
  }
  __syncthreads();
  if (threadIdx.x < J_N)
    esum_p[((long)bi * 8 + threadIdx.x) * NT_SPL + tile] =
        red[threadIdx.x] + red[8 + threadIdx.x] + red[16 + threadIdx.x] + red[24 + threadIdx.x];
}

// ---------------- D3. mid2 = combined (j-split x4) U ktqt16 -------------
__global__ void k_mid2(const float4* __restrict__ act4, const float* __restrict__ esum_p,
                       const float* __restrict__ tau, const float* __restrict__ temp,
                       const float* __restrict__ proj, float4* __restrict__ comb4,
                       _Float16* __restrict__ khi, _Float16* __restrict__ klo,
                       _Float16* __restrict__ qhi, _Float16* __restrict__ qlo) {
  __shared__ _Float16 stg[4][4096];   // 32 KB frag staging (ktqt16 branch)
  __shared__ float mk[16];
  int lane = threadIdx.x & 63;
  if (blockIdx.x < NCOMB) {
    // ---- combined: blk = (b*4 + jg)*12 + tile; j in {jg*2, jg*2+1} ----
    int blk = blockIdx.x;
    int tile = blk % 12, bjg = blk / 12;
    int jg = bjg & 3, b = bjg >> 2;
    int j0 = jg * 2;
    if (threadIdx.x < 16) {
      int i = threadIdx.x >> 1, j = j0 + (threadIdx.x & 1);
      const float* p = esum_p + ((long)(b * 8 + i) * 8 + j) * NT_SPL;
      float s = 0.f;
#pragma unroll
      for (int k = 0; k < NT_SPL; k++) s += p[k];
      float sE = sqrtf(s * (1.f / (float)SF_N) + 1e-8f);
      float ta = fabsf(tau[i * 8 + j]);
      float tv = fabsf(temp[0]) * SQRT_SF + 1e-4f;
      mk[threadIdx.x] = 1.f / (1.f + expf(-(sE - ta) / tv));
    }
    __syncthreads();
    int i4 = tile * 256 + threadIdx.x;
    if (i4 < SF4_N) {
      float4 cb[2] = {};
#pragma unroll
      for (int i = 0; i < IN_N; i++) {
#pragma unroll
        for (int jj = 0; jj < 2; jj++) {
          float4 a = act4[((long)((b * 8 + i) * 8 + j0 + jj)) * SF4_N + i4];
          float g = mk[i * 2 + jj];
          cb[jj].x += g * a.x; cb[jj].y += g * a.y;
          cb[jj].z += g * a.z; cb[jj].w += g * a.w;
        }
      }
#pragma unroll
      for (int jj = 0; jj < 2; jj++)
        comb4[((long)(b * J_N + j0 + jj)) * SF4_N + i4] = cb[jj];
    }
  } else {
    // ---- ktqt16: block = (bj, stile); wave w rows stile*16 + w*4 .. +3 ----
    int blk = blockIdx.x - NCOMB;           // 0..767
    int bj = blk / 12, stile = blk - bj * 12;
    int b = bj >> 3, j = bj & 7;
    int w = threadIdx.x >> 6;
    int ig = lane >> 4;                     // i-group 0..3
    int f4 = (lane & 15) * 4;               // f base
    int iK = b * 8 + 2 * ig, iQ = iK + 1;
    float tv = fabsf(temp[0]) * SQRT_SF + 1e-4f;
    float gK = gate_g(esum_p, iK, j, tau, tv);
    float gQ = gate_g(esum_p, iQ, j, tau, tv);
    // lane's fragment slot within a 4096-half tile (m16 filled per row)
    int slotbase = (lane >> 3) * 512 + ((lane >> 1) & 3) * 128 + (lane & 1) * 4;
    for (int rr = 0; rr < 4; rr++) {
      int m16 = w * 4 + rr;
      int s = stile * 16 + m16;
      half4 hk4 = {}, lk4 = {}, hq4 = {}, lq4 = {};
      if (s < S_N) {
        float4 kr = *(const float4*)(proj + ((long)iK * S_N + s) * 64 + f4);
        float4 qr = *(const float4*)(proj + ((long)iQ * S_N + s) * 64 + f4);
        float kv[4] = {kr.x * gK, kr.y * gK, kr.z * gK, kr.w * gK};
        float qv[4] = {qr.x * gQ, qr.y * gQ, qr.z * gQ, qr.w * gQ};
        float mkv = wave_sum(kv[0] + kv[1] + kv[2] + kv[3]) * (1.f / 256.f);
        float mqv = wave_sum(qv[0] + qv[1] + qv[2] + qv[3]) * (1.f / 256.f);
        float vk = 0.f, vq = 0.f;
#pragma unroll
        for (int q = 0; q < 4; q++) {
          float dk = kv[q] - mkv; vk += dk * dk;
          float dq = qv[q] - mqv; vq += dq * dq;
        }
        vk = wave_sum(vk) * (1.f / 256.f);
        vq = wave_sum(vq) * (1.f / 256.f);
        float ik = 1.f / sqrtf(vk + 1e-5f);
        float iq = 1.f / sqrtf(vq + 1e-5f);
#pragma unroll
        for (int q = 0; q < 4; q++) {
          float fk = (kv[q] - mkv) * ik;
          float fq = (qv[q] - mqv) * iq;
          _Float16 hk = (_Float16)fk;
          _Float16 hq = (_Float16)fq;
          hk4[q] = hk; lk4[q] = (_Float16)(fk - (float)hk);
          hq4[q] = hq; lq4[q] = (_Float16)(fq - (float)hq);
        }
      }
      int off = slotbase + m16 * 8;
      *(half4*)&stg[0][off] = hk4;
      *(half4*)&stg[1][off] = lk4;
      *(half4*)&stg[2][off] = hq4;
      *(half4*)&stg[3][off] = lq4;
    }
    __syncthreads();
    // streamed write-out: 4096 halves per array = 512 float4; 2 per thread
    long gb = ((long)bj * 12 + stile) * 4096;
    float4* dk = (float4*)(khi + gb);
    float4* dkl = (float4*)(klo + gb);
    float4* dq = (float4*)(qhi + gb);
    float4* dql = (float4*)(qlo + gb);
    const float4* s0 = (const float4*)stg[0];
    const float4* s1 = (const float4*)stg[1];
    const float4* s2 = (const float4*)stg[2];
    const float4* s3 = (const float4*)stg[3];
    int t = threadIdx.x;
    dk[t] = s0[t];  dk[t + 256] = s0[t + 256];
    dkl[t] = s1[t]; dkl[t + 256] = s1[t + 256];
    dq[t] = s2[t];  dq[t + 256] = s2[t + 256];
    dql[t] = s3[t]; dql[t + 256] = s3[t + 256];
  }
}

// ---------------- D4. xprime: LN(comb)*W2 + bparam ----------------------
__global__ void k_xp(const float* __restrict__ comb, const float* __restrict__ W2,
                     const float* __restrict__ bparam, const float* __restrict__ lns,
                     const float* __restrict__ lnb, float* __restrict__ xprime) {
  __shared__ float smem[64 * 64 + 128];
  int lane = threadIdx.x & 63;
  int tile = blockIdx.x % 12, bj = blockIdx.x / 12;
  int j = bj & 7;
  float* w2s = smem;
  float* lss = smem + 4096;
  float* lbs = smem + 4160;
  const float4* wg = (const float4*)(W2 + j * 4096);
  float4* ws4 = (float4*)w2s;
  for (int idx = threadIdx.x; idx < 1024; idx += 256) ws4[idx] = wg[idx];
  if (threadIdx.x < 64) {
    lss[threadIdx.x] = lns[j * 64 + threadIdx.x];
    lbs[threadIdx.x] = lnb[j * 64 + threadIdx.x];
  }
  __syncthreads();
  int w = threadIdx.x >> 6;
  int sbase = tile * 16 + w * 4;
  float xln[4], acc[4];
#pragma unroll
  for (int rr = 0; rr < 4; rr++) {
    int s = sbase + rr;
    int sc = (s < S_N) ? s : S_N - 1;
    float x = comb[((long)bj * S_N + sc) * 64 + lane];
    float m = wave_sum(x) * (1.f / 64.f);
    float d = x - m;
    float var = wave_sum(d * d) * (1.f / 64.f);
    xln[rr] = d / sqrtf(var + 1e-5f) * lss[lane] + lbs[lane];
    acc[rr] = bparam[(j * S_N + sc) * 64 + lane];
  }
#pragma unroll
  for (int h = 0; h < 64; h++) {
    float w2v = w2s[h * 64 + lane];
#pragma unroll
    for (int rr = 0; rr < 4; rr++) acc[rr] += lane_bc(xln[rr], h) * w2v;
  }
#pragma unroll
  for (int rr = 0; rr < 4; rr++) {
    int s = sbase + rr;
    if (s < S_N) xprime[((long)bj * S_N + s) * 64 + lane] = acc[rr];
  }
}

// ---------------- D5. rawfinal768: MFMA -> LDS scores -> softmax -> apply
// 16-row granularity: 768 blocks (3 blocks/CU, 12 waves/CU) -- fixes R4's
// occupancy collapse (256 blocks = 1/CU, 68 us). w1 never touches global
// (-18 MB HBM + write-allocate). XCD-aware mapping: xcd = bid&7 owns
// bj in [xcd*8, xcd*8+8), so each XCD's fragment working set is 1.5 MB
// (L2-resident) despite each block reading all 12 B-tiles.
__global__ void k_rawfinal(const _Float16* __restrict__ khi, const _Float16* __restrict__ klo,
                           const _Float16* __restrict__ qhi, const _Float16* __restrict__ qlo,
                           const float* __restrict__ temp, const float* __restrict__ xprime,
                           const float* __restrict__ comb, const float* __restrict__ w3,
                           const float* __restrict__ alpha, const float* __restrict__ beta,
                           const float* __restrict__ theta, const float* __restrict__ gamma,
                           float* __restrict__ out) {
  __shared__ float w1t[16 * 188];    // 12032 B
  int xcd = blockIdx.x & 7;
  int idx = blockIdx.x >> 3;        // 0..95
  int bj = xcd * 8 + idx / 12;
  int stile = idx - (idx / 12) * 12;
  int j = bj & 7;
  int w = threadIdx.x >> 6, lane = threadIdx.x & 63;
  int quad = lane >> 4, m16 = lane & 15;
  long fb = (long)bj * FRAG_BJ + lane * 8;
  // ---- MFMA: A = this stile's 16 rows; wave w computes tt = 3w..3w+2 ----
  const _Float16* ah_p = khi + fb + (long)stile * 4096;
  const _Float16* al_p = klo + fb + (long)stile * 4096;
  floatx4 acc[3] = {};
  for (int ec = 0; ec < 8; ec++) {
    half8 ah = *(const half8*)(ah_p + ec * 512);
    half8 al = *(const half8*)(al_p + ec * 512);
#pragma unroll
    for (int n = 0; n < 3; n++) {
      long bo = fb + (long)(w * 3 + n) * 4096 + ec * 512;
      half8 bh = *(const half8*)(qhi + bo);
      half8 bl = *(const half8*)(qlo + bo);
      acc[n] = __builtin_amdgcn_mfma_f32_16x16x32_f16(ah, bh, acc[n], 0, 0, 0);
      acc[n] = __builtin_amdgcn_mfma_f32_16x16x32_f16(al, bh, acc[n], 0, 0, 0);
      acc[n] = __builtin_amdgcn_mfma_f32_16x16x32_f16(ah, bl, acc[n], 0, 0, 0);
    }
  }
  float tv = fabsf(temp[0]) * SQRT_SF + 1e-4f;
  float scale = 1.f / (16.f * tv);
#pragma unroll
  for (int n = 0; n < 3; n++) {
    int t = (w * 3 + n) * 16 + m16;  // 0..191
    if (t < S_N) {
#pragma unroll
      for (int r = 0; r < 4; r++)
        w1t[(quad * 4 + r) * 188 + t] = acc[n][r] * scale;
    }
  }
  __syncthreads();
  // ---- softmax on this wave's 4 rows (rows >= S_N hold zeros: harmless) --
  int o = lane;
#pragma unroll
  for (int rr = 0; rr < 4; rr++) {
    float* row = &w1t[(w * 4 + rr) * 188];
    float v[3];
    float m = -1e30f;
#pragma unroll
    for (int q = 0; q < 3; q++) {
      int t = o + q * 64;
      v[q] = (t < S_N) ? row[t] : -1e30f;
      m = fmaxf(m, v[q]);
    }
    m = wave_max(m);
    float ssum = 0.f;
#pragma unroll
    for (int q = 0; q < 3; q++) {
      int t = o + q * 64;
      float e = (t < S_N) ? expf(v[q] - m) : 0.f;
      v[q] = e;
      ssum += e;
    }
    ssum = wave_sum(ssum);
    float invs = 1.f / ssum;
#pragma unroll
    for (int q = 0; q < 3; q++) {
      int t = o + q * 64;
      if (t < S_N) row[t] = v[q] * invs;
    }
  }
  __syncthreads();
  // ---- apply + conv + residuals on the same 4 rows ----
  float w3c[KS_N];
#pragma unroll
  for (int k = 0; k < KS_N; k++) w3c[k] = w3[j * 64 * KS_N + o * KS_N + k];
  const float* xpg = xprime + (long)bj * (S_N * 64);
  float aa = fabsf(alpha[j]), ba = fabsf(beta[j]), ta = fabsf(theta[j]), gv = gamma[j];
  int s0 = stile * 16;
  float acc2[4] = {0.f, 0.f, 0.f, 0.f};
  for (int t = 0; t < 184; t += 4) {
    float x0 = xpg[t * 64 + o];
    float x1 = xpg[(t + 1) * 64 + o];
    float x2 = xpg[(t + 2) * 64 + o];
    float x3 = xpg[(t + 3) * 64 + o];
#pragma unroll
    for (int rr = 0; rr < 4; rr++) {
      float4 wv = *(const float4*)&w1t[(w * 4 + rr) * 188 + t];
      acc2[rr] += wv.x * x0 + wv.y * x1 + wv.z * x2 + wv.w * x3;
    }
  }
#pragma unroll
  for (int t = 184; t < S_N; t++) {
    float xv = xpg[t * 64 + o];
#pragma unroll
    for (int rr = 0; rr < 4; rr++) acc2[rr] += w1t[(w * 4 + rr) * 188 + t] * xv;
  }
#pragma unroll
  for (int rr = 0; rr < 4; rr++) {
    int s = s0 + w * 4 + rr;
    if (s >= S_N) continue;
    float conv = 0.f;
#pragma unroll
    for (int k = 0; k < KS_N; k++) {
      int si = s + k - 7;
      if (si >= 0 && si < S_N) conv += xpg[si * 64 + o] * w3c[k];
    }
    float res = ba * acc2[rr] + aa * xpg[s * 64 + o] + ta * conv +
                gv * comb[((long)bj * S_N + s) * 64 + o];
    out[((long)bj * S_N + s) * 64 + o] = res;
  }
}

extern "C" void kernel_launch(void* const* d_in, const int* in_sizes, int n_in,
                              void* d_out, int out_size, void* d_ws, size_t ws_size,
                              hipStream_t stream) {
  const float* x_in   = (const float*)d_in[0];
  const float* proj   = (const float*)d_in[1];
  const float* sw     = (const float*)d_in[2];
  const float* tau    = (const float*)d_in[3];
  const float* temp   = (const float*)d_in[4];
  const float* omiga  = (const float*)d_in[5];
  const float* W2     = (const float*)d_in[6];
  const float* bparam = (const float*)d_in[7];
  const float* lns    = (const float*)d_in[8];
  const float* lnb    = (const float*)d_in[9];
  const float* alpha  = (const float*)d_in[10];
  const float* beta   = (const float*)d_in[11];
  const float* theta  = (const float*)d_in[12];
  const float* gamma  = (const float*)d_in[13];
  const float* w3     = (const float*)d_in[14];

  float* out = (float*)d_out;
  float* xprime = out + B_N * J_N * S_N * O_N;  // second output, written directly

  float* wsf = (float*)d_ws;
  float* maxp   = wsf;                            // 256 floats
  float* esum_p = wsf + 512;                      // 512*12 floats
  float* act    = wsf + 512 + 512 * NT_SPL;       // 64*8*SF_N floats = 24.5 MB
  const long ACT_N = (long)64 * 8 * SF_N;
  const long FR = (long)64 * FRAG_BJ;             // 3,145,728 halves per frag array
  _Float16* khi = (_Float16*)(act + ACT_N);
  _Float16* klo = khi + FR;
  _Float16* qhi = klo + FR;
  _Float16* qlo = qhi + FR;
  float* comb = (float*)(qlo + FR);

  k_maxabs<<<NMAXP, 256, 0, stream>>>((const float4*)x_in, maxp, (B_N * IN_N * S_N * F_N) / 4);
  k_spline<<<dim3(NT_SPL, 64), 256, 0, stream>>>((const float4*)x_in, sw, omiga, maxp,
                                                 (float4*)act, esum_p);
  k_mid2<<<NCOMB + NKT16, 256, 0, stream>>>((const float4*)act, esum_p, tau, temp,
                                            proj, (float4*)comb, khi, klo, qhi, qlo);
  k_xp<<<NXPR, 256, 0, stream>>>(comb, W2, bparam, lns, lnb, xprime);
  k_rawfinal<<<NRF, 256, 0, stream>>>(khi, klo, qhi, qlo, temp, xprime, comb,
                                      w3, alpha, beta, theta, gamma, out);
}

// Round 7
// 154.799 us; speedup vs baseline: 1.1718x; 1.0451x over previous
//
#include <hip/hip_runtime.h>
#include <math.h>

#define B_N 8
#define IN_N 8
#define J_N 8
#define S_N 187
#define F_N 64
#define O_N 64
#define C_N 67
#define KS_N 15
#define SF_N (S_N * F_N)   // 11968
#define SF4_N (SF_N / 4)   // 2992 float4s per (b,i) plane
#define SQRT_SF 0.85467470f  // sqrt(187/256)

#define NT_SPL 12           // 1024-wide idx tiles (256 float4/block) covering SF_N
#define NCOMB 384           // combined+xp blocks (8 b * 4 jg * 12 tiles)
#define NKT16 768           // ktqt16 blocks (64 bj * 12 stiles)
#define NRF 768             // rawfinal blocks (64 bj * 12 stiles)
#define NMAXP 256           // maxabs partial blocks
#define FRAG_BJ 49152       // 12 stiles * 4096 halves per bj

typedef __attribute__((ext_vector_type(8))) _Float16 half8;
typedef __attribute__((ext_vector_type(4))) _Float16 half4;
typedef __attribute__((ext_vector_type(4))) float floatx4;

// ---------------- wave helpers (wave = 64) ----------------
__device__ __forceinline__ float wave_sum(float v) {
#pragma unroll
  for (int off = 32; off > 0; off >>= 1) v += __shfl_down(v, off, 64);
  return __shfl(v, 0, 64);
}
__device__ __forceinline__ float wave_max(float v) {
#pragma unroll
  for (int off = 32; off > 0; off >>= 1) v = fmaxf(v, __shfl_down(v, off, 64));
  return __shfl(v, 0, 64);
}
__device__ __forceinline__ float bspline(float d) {
  float t2 = fmaxf(2.f - d, 0.f);
  float t1 = fmaxf(1.f - d, 0.f);
  return t2 * t2 * t2 * (1.f / 6.f) - t1 * t1 * t1 * (4.f / 6.f);
}
__device__ __forceinline__ float get_inv095(const float* __restrict__ maxp) {
  int lane = threadIdx.x & 63;
  float m = 0.f;
#pragma unroll
  for (int k = 0; k < NMAXP / 64; k++) m = fmaxf(m, maxp[lane + k * 64]);
  return 0.95f / (wave_max(m) + 1e-8f);
}
// gate = (sqrtE/tau) * sigmoid((sqrtE-tau)/tv) from the 12 per-tile partials
__device__ __forceinline__ float gate_g(const float* __restrict__ esum_p, int bi, int j,
                                        const float* __restrict__ tau, float tv) {
  const float* p = esum_p + ((long)bi * 8 + j) * NT_SPL;
  float s = 0.f;
#pragma unroll
  for (int k = 0; k < NT_SPL; k++) s += p[k];
  float sE = sqrtf(s * (1.f / (float)SF_N) + 1e-8f);
  float ta = fabsf(tau[(bi & 7) * 8 + j]);
  return (sE / (ta + 1e-8f)) / (1.f + expf(-(sE - ta) / tv));
}

// ---------------- D1. global max |x| -> per-block maxima ----------------
__global__ void k_maxabs(const float4* __restrict__ x, float* __restrict__ maxp, int n4) {
  __shared__ float red[4];
  int tid = blockIdx.x * 256 + threadIdx.x;
  float m = 0.f;
  for (int i = tid; i < n4; i += gridDim.x * 256) {
    float4 v = x[i];
    m = fmaxf(m, fmaxf(fmaxf(fabsf(v.x), fabsf(v.y)), fmaxf(fabsf(v.z), fabsf(v.w))));
  }
  m = wave_max(m);
  if ((threadIdx.x & 63) == 0) red[threadIdx.x >> 6] = m;
  __syncthreads();
  if (threadIdx.x == 0)
    maxp[blockIdx.x] = fmaxf(fmaxf(red[0], red[1]), fmaxf(red[2], red[3]));
}

// ---------------- D2. spline ONCE (float4-vectorized): act + energies ---
// Weight tile transposed to [c][j]: each tap is 2x ds_read_b128 instead of
// 8x stride-67 ds_read_b32 (~2x fewer LDS cycles on the hot loop).
__global__ void k_spline(const float4* __restrict__ x4, const float* __restrict__ sw,
                         const float* __restrict__ omiga, const float* __restrict__ maxp,
                         float4* __restrict__ act4, float* __restrict__ esum_p) {
  int tile = blockIdx.x, bi = blockIdx.y;
  int i = bi & 7;
  __shared__ float wl[C_N * 8];   // [c][j]
  __shared__ float aom[J_N];
  __shared__ float red[4 * J_N];
  for (int t = threadIdx.x; t < J_N * C_N; t += 256) {
    int j = t / C_N, c = t - j * C_N;
    wl[c * 8 + j] = sw[i * J_N * C_N + t];
  }
  if (threadIdx.x < J_N) aom[threadIdx.x] = fabsf(omiga[i * J_N + threadIdx.x]);
  int lane = threadIdx.x & 63, wid = threadIdx.x >> 6;
  float inv = get_inv095(maxp);
  __syncthreads();
  int i4 = tile * 256 + threadIdx.x;
  float e[J_N] = {0, 0, 0, 0, 0, 0, 0, 0};
  if (i4 < SF4_N) {
    float4 xv = x4[(long)bi * SF4_N + i4];
    float xs[4] = {xv.x, xv.y, xv.z, xv.w};
    float4 av[J_N];
#pragma unroll
    for (int c = 0; c < 4; c++) {
      float x = xs[c];
      float xn = fminf(fmaxf(x * inv, -0.99f), 0.99f);
      float u = (xn + 1.f) * 33.f;
      int c0 = (int)floorf(u) - 1;
      float sm[J_N] = {0, 0, 0, 0, 0, 0, 0, 0};
#pragma unroll
      for (int kk = 0; kk < 4; kk++) {
        int cc = c0 + kk;
        if (cc >= 0 && cc < C_N) {
          float bas = bspline(fabsf(u - (float)cc));
          const float4* wp = (const float4*)(wl + cc * 8);
          float4 wa = wp[0], wb = wp[1];
          sm[0] += bas * wa.x; sm[1] += bas * wa.y;
          sm[2] += bas * wa.z; sm[3] += bas * wa.w;
          sm[4] += bas * wb.x; sm[5] += bas * wb.y;
          sm[6] += bas * wb.z; sm[7] += bas * wb.w;
        }
      }
#pragma unroll
      for (int j = 0; j < J_N; j++) {
        float a = sm[j] + aom[j] * x;
        (&av[j].x)[c] = a;
        e[j] += a * a;
      }
    }
#pragma unroll
    for (int j = 0; j < J_N; j++) act4[((long)(bi * 8 + j)) * SF4_N + i4] = av[j];
  }
#pragma unroll
  for (int j = 0; j < J_N; j++) {
    float v = e[j];
#pragma unroll
    for (int off = 32; off > 0; off >>= 1) v += __shfl_down(v, off, 64);
    if (lane == 0) red[wid * J_N + j] = v;
  }
  __syncthreads();
  if (threadIdx.x < J_N)
    esum_p[((long)bi * 8 + threadIdx.x) * NT_SPL + tile] =
        red[threadIdx.x] + red[8 + threadIdx.x] + red[16 + threadIdx.x] + red[24 + threadIdx.x];
}

// ---------------- D3. mid2 = (combined+xp fused) U ktqt16 ---------------
// combined+xp: a combined block already holds complete f-rows (16 s x 64 f
// per j), which is exactly xp's granularity -> LN + W2 matmul done in-place.
// Saves the 12 MB comb re-read, the 768-block k_xp launch, and W2
// re-staging. comb is still written once (rawfinal's gamma-residual).
__global__ void k_mid2(const float4* __restrict__ act4, const float* __restrict__ esum_p,
                       const float* __restrict__ tau, const float* __restrict__ temp,
                       const float* __restrict__ proj, const float* __restrict__ W2,
                       const float* __restrict__ bparam, const float* __restrict__ lns,
                       const float* __restrict__ lnb, float4* __restrict__ comb4,
                       float* __restrict__ xprime,
                       _Float16* __restrict__ khi, _Float16* __restrict__ klo,
                       _Float16* __restrict__ qhi, _Float16* __restrict__ qlo) {
  __shared__ float smem[8192 + 16 + 256];  // 33.9 KB: W2(2j) | mk | lss | lbs ; aliased by stg
  int lane = threadIdx.x & 63;
  if (blockIdx.x < NCOMB) {
    // ---- combined+xp: blk = (b*4 + jg)*12 + tile; j in {jg*2, jg*2+1} ----
    int blk = blockIdx.x;
    int tile = blk % 12, bjg = blk / 12;
    int jg = bjg & 3, b = bjg >> 2;
    int j0 = jg * 2;
    float* w2s = smem;             // [2][64][64]
    float* mk  = smem + 8192;      // 16
    float* lss = smem + 8208;      // [2][64]
    float* lbs = smem + 8336;      // [2][64]
    {
      const float4* wg = (const float4*)(W2 + j0 * 4096);
      float4* ws4 = (float4*)w2s;
      for (int t = threadIdx.x; t < 2048; t += 256) ws4[t] = wg[t];
    }
    if (threadIdx.x < 128) {
      int jj = threadIdx.x >> 6, f = threadIdx.x & 63;
      lss[threadIdx.x] = lns[(j0 + jj) * 64 + f];
      lbs[threadIdx.x] = lnb[(j0 + jj) * 64 + f];
    }
    if (threadIdx.x < 16) {
      int i = threadIdx.x >> 1, j = j0 + (threadIdx.x & 1);
      const float* p = esum_p + ((long)(b * 8 + i) * 8 + j) * NT_SPL;
      float s = 0.f;
#pragma unroll
      for (int k = 0; k < NT_SPL; k++) s += p[k];
      float sE = sqrtf(s * (1.f / (float)SF_N) + 1e-8f);
      float ta = fabsf(tau[i * 8 + j]);
      float tv = fabsf(temp[0]) * SQRT_SF + 1e-4f;
      mk[threadIdx.x] = 1.f / (1.f + expf(-(sE - ta) / tv));
    }
    __syncthreads();
    int i4 = tile * 256 + threadIdx.x;
    if (i4 < SF4_N) {
      float4 cb[2] = {};
#pragma unroll
      for (int i = 0; i < IN_N; i++) {
#pragma unroll
        for (int jj = 0; jj < 2; jj++) {
          float4 a = act4[((long)((b * 8 + i) * 8 + j0 + jj)) * SF4_N + i4];
          float g = mk[i * 2 + jj];
          cb[jj].x += g * a.x; cb[jj].y += g * a.y;
          cb[jj].z += g * a.z; cb[jj].w += g * a.w;
        }
      }
#pragma unroll
      for (int jj = 0; jj < 2; jj++)
        comb4[((long)(b * J_N + j0 + jj)) * SF4_N + i4] = cb[jj];
      // ---- fused xp: LN over f (16-lane row) + W2 matmul + bparam ----
      int s = i4 >> 4;                       // global seq row (< S_N by guard)
      int fx = (threadIdx.x & 15) * 4;       // this lane's 4 o/h positions
      int g0 = lane & 48;                    // 16-lane group base within wave
#pragma unroll
      for (int jj = 0; jj < 2; jj++) {
        float4 c = cb[jj];
        float ls = c.x + c.y + c.z + c.w;
#pragma unroll
        for (int m = 1; m <= 8; m <<= 1) ls += __shfl_xor(ls, m, 64);
        float mean = ls * (1.f / 64.f);
        float d0 = c.x - mean, d1 = c.y - mean, d2 = c.z - mean, d3 = c.w - mean;
        float lv = d0 * d0 + d1 * d1 + d2 * d2 + d3 * d3;
#pragma unroll
        for (int m = 1; m <= 8; m <<= 1) lv += __shfl_xor(lv, m, 64);
        float invsd = 1.f / sqrtf(lv * (1.f / 64.f) + 1e-5f);
        float xln0 = d0 * invsd * lss[jj * 64 + fx + 0] + lbs[jj * 64 + fx + 0];
        float xln1 = d1 * invsd * lss[jj * 64 + fx + 1] + lbs[jj * 64 + fx + 1];
        float xln2 = d2 * invsd * lss[jj * 64 + fx + 2] + lbs[jj * 64 + fx + 2];
        float xln3 = d3 * invsd * lss[jj * 64 + fx + 3] + lbs[jj * 64 + fx + 3];
        float4 bp = *(const float4*)(bparam + ((long)(j0 + jj) * S_N + s) * 64 + fx);
        float a0 = bp.x, a1 = bp.y, a2 = bp.z, a3 = bp.w;
#pragma unroll
        for (int t16 = 0; t16 < 16; t16++) {
          int src = g0 + t16;
          float h0 = __shfl(xln0, src, 64);
          float h1 = __shfl(xln1, src, 64);
          float h2 = __shfl(xln2, src, 64);
          float h3 = __shfl(xln3, src, 64);
          const float* wrow = w2s + jj * 4096 + (t16 * 4) * 64 + fx;
          float4 w0 = *(const float4*)(wrow);
          float4 w1 = *(const float4*)(wrow + 64);
          float4 w2v = *(const float4*)(wrow + 128);
          float4 w3v = *(const float4*)(wrow + 192);
          a0 += h0 * w0.x + h1 * w1.x + h2 * w2v.x + h3 * w3v.x;
          a1 += h0 * w0.y + h1 * w1.y + h2 * w2v.y + h3 * w3v.y;
          a2 += h0 * w0.z + h1 * w1.z + h2 * w2v.z + h3 * w3v.z;
          a3 += h0 * w0.w + h1 * w1.w + h2 * w2v.w + h3 * w3v.w;
        }
        float4 o4 = {a0, a1, a2, a3};
        *(float4*)(xprime + (((long)(b * J_N + j0 + jj)) * S_N + s) * 64 + fx) = o4;
      }
    }
  } else {
    // ---- ktqt16: block = (bj, stile); wave w rows stile*16 + w*4 .. +3 ----
    _Float16* stg = (_Float16*)smem;        // [4][4096] halves = 32 KB
    int blk = blockIdx.x - NCOMB;           // 0..767
    int bj = blk / 12, stile = blk - bj * 12;
    int b = bj >> 3, j = bj & 7;
    int w = threadIdx.x >> 6;
    int ig = lane >> 4;                     // i-group 0..3
    int f4 = (lane & 15) * 4;               // f base
    int iK = b * 8 + 2 * ig, iQ = iK + 1;
    float tv = fabsf(temp[0]) * SQRT_SF + 1e-4f;
    float gK = gate_g(esum_p, iK, j, tau, tv);
    float gQ = gate_g(esum_p, iQ, j, tau, tv);
    // lane's fragment slot within a 4096-half tile (m16 filled per row)
    int slotbase = (lane >> 3) * 512 + ((lane >> 1) & 3) * 128 + (lane & 1) * 4;
    for (int rr = 0; rr < 4; rr++) {
      int m16 = w * 4 + rr;
      int s = stile * 16 + m16;
      half4 hk4 = {}, lk4 = {}, hq4 = {}, lq4 = {};
      if (s < S_N) {
        float4 kr = *(const float4*)(proj + ((long)iK * S_N + s) * 64 + f4);
        float4 qr = *(const float4*)(proj + ((long)iQ * S_N + s) * 64 + f4);
        float kv[4] = {kr.x * gK, kr.y * gK, kr.z * gK, kr.w * gK};
        float qv[4] = {qr.x * gQ, qr.y * gQ, qr.z * gQ, qr.w * gQ};
        float mkv = wave_sum(kv[0] + kv[1] + kv[2] + kv[3]) * (1.f / 256.f);
        float mqv = wave_sum(qv[0] + qv[1] + qv[2] + qv[3]) * (1.f / 256.f);
        float vk = 0.f, vq = 0.f;
#pragma unroll
        for (int q = 0; q < 4; q++) {
          float dk = kv[q] - mkv; vk += dk * dk;
          float dq = qv[q] - mqv; vq += dq * dq;
        }
        vk = wave_sum(vk) * (1.f / 256.f);
        vq = wave_sum(vq) * (1.f / 256.f);
        float ik = 1.f / sqrtf(vk + 1e-5f);
        float iq = 1.f / sqrtf(vq + 1e-5f);
#pragma unroll
        for (int q = 0; q < 4; q++) {
          float fk = (kv[q] - mkv) * ik;
          float fq = (qv[q] - mqv) * iq;
          _Float16 hk = (_Float16)fk;
          _Float16 hq = (_Float16)fq;
          hk4[q] = hk; lk4[q] = (_Float16)(fk - (float)hk);
          hq4[q] = hq; lq4[q] = (_Float16)(fq - (float)hq);
        }
      }
      int off = slotbase + m16 * 8;
      *(half4*)&stg[0 * 4096 + off] = hk4;
      *(half4*)&stg[1 * 4096 + off] = lk4;
      *(half4*)&stg[2 * 4096 + off] = hq4;
      *(half4*)&stg[3 * 4096 + off] = lq4;
    }
    __syncthreads();
    // streamed write-out: 4096 halves per array = 512 float4; 2 per thread
    long gb = ((long)bj * 12 + stile) * 4096;
    float4* dk = (float4*)(khi + gb);
    float4* dkl = (float4*)(klo + gb);
    float4* dq = (float4*)(qhi + gb);
    float4* dql = (float4*)(qlo + gb);
    const float4* s0 = (const float4*)(stg + 0 * 4096);
    const float4* s1 = (const float4*)(stg + 1 * 4096);
    const float4* s2 = (const float4*)(stg + 2 * 4096);
    const float4* s3 = (const float4*)(stg + 3 * 4096);
    int t = threadIdx.x;
    dk[t] = s0[t];  dk[t + 256] = s0[t + 256];
    dkl[t] = s1[t]; dkl[t + 256] = s1[t + 256];
    dq[t] = s2[t];  dq[t + 256] = s2[t + 256];
    dql[t] = s3[t]; dql[t + 256] = s3[t + 256];
  }
}

// ---------------- D4. rawfinal768: MFMA -> LDS scores -> softmax -> apply
// 768 blocks (3/CU, 12 waves/CU); w1 never touches global. XCD-aware
// mapping keeps each bj's 192 KB fragment set on one XCD's L2.
__global__ void k_rawfinal(const _Float16* __restrict__ khi, const _Float16* __restrict__ klo,
                           const _Float16* __restrict__ qhi, const _Float16* __restrict__ qlo,
                           const float* __restrict__ temp, const float* __restrict__ xprime,
                           const float* __restrict__ comb, const float* __restrict__ w3,
                           const float* __restrict__ alpha, const float* __restrict__ beta,
                           const float* __restrict__ theta, const float* __restrict__ gamma,
                           float* __restrict__ out) {
  __shared__ float w1t[16 * 188];    // 12032 B
  int xcd = blockIdx.x & 7;
  int idx = blockIdx.x >> 3;        // 0..95
  int bj = xcd * 8 + idx / 12;
  int stile = idx - (idx / 12) * 12;
  int j = bj & 7;
  int w = threadIdx.x >> 6, lane = threadIdx.x & 63;
  int quad = lane >> 4, m16 = lane & 15;
  long fb = (long)bj * FRAG_BJ + lane * 8;
  // ---- MFMA: A = this stile's 16 rows; wave w computes tt = 3w..3w+2 ----
  const _Float16* ah_p = khi + fb + (long)stile * 4096;
  const _Float16* al_p = klo + fb + (long)stile * 4096;
  floatx4 acc[3] = {};
  for (int ec = 0; ec < 8; ec++) {
    half8 ah = *(const half8*)(ah_p + ec * 512);
    half8 al = *(const half8*)(al_p + ec * 512);
#pragma unroll
    for (int n = 0; n < 3; n++) {
      long bo = fb + (long)(w * 3 + n) * 4096 + ec * 512;
      half8 bh = *(const half8*)(qhi + bo);
      half8 bl = *(const half8*)(qlo + bo);
      acc[n] = __builtin_amdgcn_mfma_f32_16x16x32_f16(ah, bh, acc[n], 0, 0, 0);
      acc[n] = __builtin_amdgcn_mfma_f32_16x16x32_f16(al, bh, acc[n], 0, 0, 0);
      acc[n] = __builtin_amdgcn_mfma_f32_16x16x32_f16(ah, bl, acc[n], 0, 0, 0);
    }
  }
  float tv = fabsf(temp[0]) * SQRT_SF + 1e-4f;
  float scale = 1.f / (16.f * tv);
#pragma unroll
  for (int n = 0; n < 3; n++) {
    int t = (w * 3 + n) * 16 + m16;  // 0..191
    if (t < S_N) {
#pragma unroll
      for (int r = 0; r < 4; r++)
        w1t[(quad * 4 + r) * 188 + t] = acc[n][r] * scale;
    }
  }
  __syncthreads();
  // ---- softmax on this wave's 4 rows ----
  int o = lane;
#pragma unroll
  for (int rr = 0; rr < 4; rr++) {
    float* row = &w1t[(w * 4 + rr) * 188];
    float v[3];
    float m = -1e30f;
#pragma unroll
    for (int q = 0; q < 3; q++) {
      int t = o + q * 64;
      v[q] = (t < S_N) ? row[t] : -1e30f;
      m = fmaxf(m, v[q]);
    }
    m = wave_max(m);
    float ssum = 0.f;
#pragma unroll
    for (int q = 0; q < 3; q++) {
      int t = o + q * 64;
      float e = (t < S_N) ? expf(v[q] - m) : 0.f;
      v[q] = e;
      ssum += e;
    }
    ssum = wave_sum(ssum);
    float invs = 1.f / ssum;
#pragma unroll
    for (int q = 0; q < 3; q++) {
      int t = o + q * 64;
      if (t < S_N) row[t] = v[q] * invs;
    }
  }
  __syncthreads();
  // ---- apply + conv + residuals on the same 4 rows ----
  float w3c[KS_N];
#pragma unroll
  for (int k = 0; k < KS_N; k++) w3c[k] = w3[j * 64 * KS_N + o * KS_N + k];
  const float* xpg = xprime + (long)bj * (S_N * 64);
  float aa = fabsf(alpha[j]), ba = fabsf(beta[j]), ta = fabsf(theta[j]), gv = gamma[j];
  int s0 = stile * 16;
  float acc2[4] = {0.f, 0.f, 0.f, 0.f};
  for (int t = 0; t < 184; t += 4) {
    float x0 = xpg[t * 64 + o];
    float x1 = xpg[(t + 1) * 64 + o];
    float x2 = xpg[(t + 2) * 64 + o];
    float x3 = xpg[(t + 3) * 64 + o];
#pragma unroll
    for (int rr = 0; rr < 4; rr++) {
      float4 wv = *(const float4*)&w1t[(w * 4 + rr) * 188 + t];
      acc2[rr] += wv.x * x0 + wv.y * x1 + wv.z * x2 + wv.w * x3;
    }
  }
#pragma unroll
  for (int t = 184; t < S_N; t++) {
    float xv = xpg[t * 64 + o];
#pragma unroll
    for (int rr = 0; rr < 4; rr++) acc2[rr] += w1t[(w * 4 + rr) * 188 + t] * xv;
  }
#pragma unroll
  for (int rr = 0; rr < 4; rr++) {
    int s = s0 + w * 4 + rr;
    if (s >= S_N) continue;
    float conv = 0.f;
#pragma unroll
    for (int k = 0; k < KS_N; k++) {
      int si = s + k - 7;
      if (si >= 0 && si < S_N) conv += xpg[si * 64 + o] * w3c[k];
    }
    float res = ba * acc2[rr] + aa * xpg[s * 64 + o] + ta * conv +
                gv * comb[((long)bj * S_N + s) * 64 + o];
    out[((long)bj * S_N + s) * 64 + o] = res;
  }
}

extern "C" void kernel_launch(void* const* d_in, const int* in_sizes, int n_in,
                              void* d_out, int out_size, void* d_ws, size_t ws_size,
                              hipStream_t stream) {
  const float* x_in   = (const float*)d_in[0];
  const float* proj   = (const float*)d_in[1];
  const float* sw     = (const float*)d_in[2];
  const float* tau    = (const float*)d_in[3];
  const float* temp   = (const float*)d_in[4];
  const float* omiga  = (const float*)d_in[5];
  const float* W2     = (const float*)d_in[6];
  const float* bparam = (const float*)d_in[7];
  const float* lns    = (const float*)d_in[8];
  const float* lnb    = (const float*)d_in[9];
  const float* alpha  = (const float*)d_in[10];
  const float* beta   = (const float*)d_in[11];
  const float* theta  = (const float*)d_in[12];
  const float* gamma  = (const float*)d_in[13];
  const float* w3     = (const float*)d_in[14];

  float* out = (float*)d_out;
  float* xprime = out + B_N * J_N * S_N * O_N;  // second output, written directly

  float* wsf = (float*)d_ws;
  float* maxp   = wsf;                            // 256 floats
  float* esum_p = wsf + 512;                      // 512*12 floats
  float* act    = wsf + 512 + 512 * NT_SPL;       // 64*8*SF_N floats = 24.5 MB
  const long ACT_N = (long)64 * 8 * SF_N;
  const long FR = (long)64 * FRAG_BJ;             // 3,145,728 halves per frag array
  _Float16* khi = (_Float16*)(act + ACT_N);
  _Float16* klo = khi + FR;
  _Float16* qhi = klo + FR;
  _Float16* qlo = qhi + FR;
  float* comb = (float*)(qlo + FR);

  k_maxabs<<<NMAXP, 256, 0, stream>>>((const float4*)x_in, maxp, (B_N * IN_N * S_N * F_N) / 4);
  k_spline<<<dim3(NT_SPL, 64), 256, 0, stream>>>((const float4*)x_in, sw, omiga, maxp,
                                                 (float4*)act, esum_p);
  k_mid2<<<NCOMB + NKT16, 256, 0, stream>>>((const float4*)act, esum_p, tau, temp, proj,
                                            W2, bparam, lns, lnb, (float4*)comb, xprime,
                                            khi, klo, qhi, qlo);
  k_rawfinal<<<NRF, 256, 0, stream>>>(khi, klo, qhi, qlo, temp, xprime, comb,
                                      w3, alpha, beta, theta, gamma, out);
}

// Round 8
// 146.346 us; speedup vs baseline: 1.2395x; 1.0578x over previous
//
#include <hip/hip_runtime.h>
#include <math.h>

#define B_N 8
#define IN_N 8
#define J_N 8
#define S_N 187
#define F_N 64
#define O_N 64
#define C_N 67
#define KS_N 15
#define SF_N (S_N * F_N)   // 11968
#define SF4_N (SF_N / 4)   // 2992 float4s per (b,i) plane
#define SQRT_SF 0.85467470f  // sqrt(187/256)

#define NT_SPL 12           // 1024-wide idx tiles (256 float4/block) covering SF_N
#define NCOMB 384           // combined+xp blocks (8 b * 4 jg * 12 tiles)
#define NKT16 768           // ktqt16 blocks (64 bj * 12 stiles)
#define NRF 768             // rawfinal blocks (64 bj * 12 stiles)
#define NMAXP 256           // maxabs partial blocks
#define FRAG_BJ 49152       // 12 stiles * 4096 halves per bj
#define W1STRIDE 196        // w1t row stride: 16B-aligned (196*4%16==0), bank-staggered

typedef __attribute__((ext_vector_type(8))) _Float16 half8;
typedef __attribute__((ext_vector_type(4))) _Float16 half4;
typedef __attribute__((ext_vector_type(4))) float floatx4;

// ---------------- wave helpers (wave = 64) ----------------
__device__ __forceinline__ float wave_sum(float v) {
#pragma unroll
  for (int off = 32; off > 0; off >>= 1) v += __shfl_down(v, off, 64);
  return __shfl(v, 0, 64);
}
__device__ __forceinline__ float wave_max(float v) {
#pragma unroll
  for (int off = 32; off > 0; off >>= 1) v = fmaxf(v, __shfl_down(v, off, 64));
  return __shfl(v, 0, 64);
}
__device__ __forceinline__ float bspline(float d) {
  float t2 = fmaxf(2.f - d, 0.f);
  float t1 = fmaxf(1.f - d, 0.f);
  return t2 * t2 * t2 * (1.f / 6.f) - t1 * t1 * t1 * (4.f / 6.f);
}
__device__ __forceinline__ float get_inv095(const float* __restrict__ maxp) {
  int lane = threadIdx.x & 63;
  float m = 0.f;
#pragma unroll
  for (int k = 0; k < NMAXP / 64; k++) m = fmaxf(m, maxp[lane + k * 64]);
  return 0.95f / (wave_max(m) + 1e-8f);
}
// gate = (sqrtE/tau) * sigmoid((sqrtE-tau)/tv) from the 12 per-tile partials
__device__ __forceinline__ float gate_g(const float* __restrict__ esum_p, int bi, int j,
                                        const float* __restrict__ tau, float tv) {
  const float* p = esum_p + ((long)bi * 8 + j) * NT_SPL;
  float s = 0.f;
#pragma unroll
  for (int k = 0; k < NT_SPL; k++) s += p[k];
  float sE = sqrtf(s * (1.f / (float)SF_N) + 1e-8f);
  float ta = fabsf(tau[(bi & 7) * 8 + j]);
  return (sE / (ta + 1e-8f)) / (1.f + expf(-(sE - ta) / tv));
}

// ---------------- D1. global max |x| -> per-block maxima ----------------
__global__ void k_maxabs(const float4* __restrict__ x, float* __restrict__ maxp, int n4) {
  __shared__ float red[4];
  int tid = blockIdx.x * 256 + threadIdx.x;
  float m = 0.f;
  for (int i = tid; i < n4; i += gridDim.x * 256) {
    float4 v = x[i];
    m = fmaxf(m, fmaxf(fmaxf(fabsf(v.x), fabsf(v.y)), fmaxf(fabsf(v.z), fabsf(v.w))));
  }
  m = wave_max(m);
  if ((threadIdx.x & 63) == 0) red[threadIdx.x >> 6] = m;
  __syncthreads();
  if (threadIdx.x == 0)
    maxp[blockIdx.x] = fmaxf(fmaxf(red[0], red[1]), fmaxf(red[2], red[3]));
}

// ---------------- D2. spline ONCE (float4-vectorized): act + energies ---
__global__ void k_spline(const float4* __restrict__ x4, const float* __restrict__ sw,
                         const float* __restrict__ omiga, const float* __restrict__ maxp,
                         float4* __restrict__ act4, float* __restrict__ esum_p) {
  int tile = blockIdx.x, bi = blockIdx.y;
  int i = bi & 7;
  __shared__ float wl[C_N * 8];   // [c][j]
  __shared__ float aom[J_N];
  __shared__ float red[4 * J_N];
  for (int t = threadIdx.x; t < J_N * C_N; t += 256) {
    int j = t / C_N, c = t - j * C_N;
    wl[c * 8 + j] = sw[i * J_N * C_N + t];
  }
  if (threadIdx.x < J_N) aom[threadIdx.x] = fabsf(omiga[i * J_N + threadIdx.x]);
  int lane = threadIdx.x & 63, wid = threadIdx.x >> 6;
  float inv = get_inv095(maxp);
  __syncthreads();
  int i4 = tile * 256 + threadIdx.x;
  float e[J_N] = {0, 0, 0, 0, 0, 0, 0, 0};
  if (i4 < SF4_N) {
    float4 xv = x4[(long)bi * SF4_N + i4];
    float xs[4] = {xv.x, xv.y, xv.z, xv.w};
    float4 av[J_N];
#pragma unroll
    for (int c = 0; c < 4; c++) {
      float x = xs[c];
      float xn = fminf(fmaxf(x * inv, -0.99f), 0.99f);
      float u = (xn + 1.f) * 33.f;
      int c0 = (int)floorf(u) - 1;
      float sm[J_N] = {0, 0, 0, 0, 0, 0, 0, 0};
#pragma unroll
      for (int kk = 0; kk < 4; kk++) {
        int cc = c0 + kk;
        if (cc >= 0 && cc < C_N) {
          float bas = bspline(fabsf(u - (float)cc));
          const float4* wp = (const float4*)(wl + cc * 8);
          float4 wa = wp[0], wb = wp[1];
          sm[0] += bas * wa.x; sm[1] += bas * wa.y;
          sm[2] += bas * wa.z; sm[3] += bas * wa.w;
          sm[4] += bas * wb.x; sm[5] += bas * wb.y;
          sm[6] += bas * wb.z; sm[7] += bas * wb.w;
        }
      }
#pragma unroll
      for (int j = 0; j < J_N; j++) {
        float a = sm[j] + aom[j] * x;
        (&av[j].x)[c] = a;
        e[j] += a * a;
      }
    }
#pragma unroll
    for (int j = 0; j < J_N; j++) act4[((long)(bi * 8 + j)) * SF4_N + i4] = av[j];
  }
#pragma unroll
  for (int j = 0; j < J_N; j++) {
    float v = e[j];
#pragma unroll
    for (int off = 32; off > 0; off >>= 1) v += __shfl_down(v, off, 64);
    if (lane == 0) red[wid * J_N + j] = v;
  }
  __syncthreads();
  if (threadIdx.x < J_N)
    esum_p[((long)bi * 8 + threadIdx.x) * NT_SPL + tile] =
        red[threadIdx.x] + red[8 + threadIdx.x] + red[16 + threadIdx.x] + red[24 + threadIdx.x];
}

// ---------------- D3. mid2 = (combined+xp fused) U ktqt16 ---------------
__global__ void k_mid2(const float4* __restrict__ act4, const float* __restrict__ esum_p,
                       const float* __restrict__ tau, const float* __restrict__ temp,
                       const float* __restrict__ proj, const float* __restrict__ W2,
                       const float* __restrict__ bparam, const float* __restrict__ lns,
                       const float* __restrict__ lnb, float4* __restrict__ comb4,
                       float* __restrict__ xprime,
                       _Float16* __restrict__ khi, _Float16* __restrict__ klo,
                       _Float16* __restrict__ qhi, _Float16* __restrict__ qlo) {
  __shared__ float smem[8192 + 16 + 256];  // 33.9 KB: W2(2j) | mk | lss | lbs ; aliased by stg
  int lane = threadIdx.x & 63;
  if (blockIdx.x < NCOMB) {
    // ---- combined+xp: blk = (b*4 + jg)*12 + tile; j in {jg*2, jg*2+1} ----
    int blk = blockIdx.x;
    int tile = blk % 12, bjg = blk / 12;
    int jg = bjg & 3, b = bjg >> 2;
    int j0 = jg * 2;
    float* w2s = smem;             // [2][64][64]
    float* mk  = smem + 8192;      // 16
    float* lss = smem + 8208;      // [2][64]
    float* lbs = smem + 8336;      // [2][64]
    {
      const float4* wg = (const float4*)(W2 + j0 * 4096);
      float4* ws4 = (float4*)w2s;
      for (int t = threadIdx.x; t < 2048; t += 256) ws4[t] = wg[t];
    }
    if (threadIdx.x < 128) {
      int jj = threadIdx.x >> 6, f = threadIdx.x & 63;
      lss[threadIdx.x] = lns[(j0 + jj) * 64 + f];
      lbs[threadIdx.x] = lnb[(j0 + jj) * 64 + f];
    }
    if (threadIdx.x < 16) {
      int i = threadIdx.x >> 1, j = j0 + (threadIdx.x & 1);
      const float* p = esum_p + ((long)(b * 8 + i) * 8 + j) * NT_SPL;
      float s = 0.f;
#pragma unroll
      for (int k = 0; k < NT_SPL; k++) s += p[k];
      float sE = sqrtf(s * (1.f / (float)SF_N) + 1e-8f);
      float ta = fabsf(tau[i * 8 + j]);
      float tv = fabsf(temp[0]) * SQRT_SF + 1e-4f;
      mk[threadIdx.x] = 1.f / (1.f + expf(-(sE - ta) / tv));
    }
    __syncthreads();
    int i4 = tile * 256 + threadIdx.x;
    if (i4 < SF4_N) {
      float4 cb[2] = {};
#pragma unroll
      for (int i = 0; i < IN_N; i++) {
#pragma unroll
        for (int jj = 0; jj < 2; jj++) {
          float4 a = act4[((long)((b * 8 + i) * 8 + j0 + jj)) * SF4_N + i4];
          float g = mk[i * 2 + jj];
          cb[jj].x += g * a.x; cb[jj].y += g * a.y;
          cb[jj].z += g * a.z; cb[jj].w += g * a.w;
        }
      }
#pragma unroll
      for (int jj = 0; jj < 2; jj++)
        comb4[((long)(b * J_N + j0 + jj)) * SF4_N + i4] = cb[jj];
      // ---- fused xp: LN over f (16-lane row) + W2 matmul + bparam ----
      int s = i4 >> 4;                       // global seq row (< S_N by guard)
      int fx = (threadIdx.x & 15) * 4;       // this lane's 4 o/h positions
      int g0 = lane & 48;                    // 16-lane group base within wave
#pragma unroll
      for (int jj = 0; jj < 2; jj++) {
        float4 c = cb[jj];
        float ls = c.x + c.y + c.z + c.w;
#pragma unroll
        for (int m = 1; m <= 8; m <<= 1) ls += __shfl_xor(ls, m, 64);
        float mean = ls * (1.f / 64.f);
        float d0 = c.x - mean, d1 = c.y - mean, d2 = c.z - mean, d3 = c.w - mean;
        float lv = d0 * d0 + d1 * d1 + d2 * d2 + d3 * d3;
#pragma unroll
        for (int m = 1; m <= 8; m <<= 1) lv += __shfl_xor(lv, m, 64);
        float invsd = 1.f / sqrtf(lv * (1.f / 64.f) + 1e-5f);
        float xln0 = d0 * invsd * lss[jj * 64 + fx + 0] + lbs[jj * 64 + fx + 0];
        float xln1 = d1 * invsd * lss[jj * 64 + fx + 1] + lbs[jj * 64 + fx + 1];
        float xln2 = d2 * invsd * lss[jj * 64 + fx + 2] + lbs[jj * 64 + fx + 2];
        float xln3 = d3 * invsd * lss[jj * 64 + fx + 3] + lbs[jj * 64 + fx + 3];
        float4 bp = *(const float4*)(bparam + ((long)(j0 + jj) * S_N + s) * 64 + fx);
        float a0 = bp.x, a1 = bp.y, a2 = bp.z, a3 = bp.w;
#pragma unroll
        for (int t16 = 0; t16 < 16; t16++) {
          int src = g0 + t16;
          float h0 = __shfl(xln0, src, 64);
          float h1 = __shfl(xln1, src, 64);
          float h2 = __shfl(xln2, src, 64);
          float h3 = __shfl(xln3, src, 64);
          const float* wrow = w2s + jj * 4096 + (t16 * 4) * 64 + fx;
          float4 w0 = *(const float4*)(wrow);
          float4 w1 = *(const float4*)(wrow + 64);
          float4 w2v = *(const float4*)(wrow + 128);
          float4 w3v = *(const float4*)(wrow + 192);
          a0 += h0 * w0.x + h1 * w1.x + h2 * w2v.x + h3 * w3v.x;
          a1 += h0 * w0.y + h1 * w1.y + h2 * w2v.y + h3 * w3v.y;
          a2 += h0 * w0.z + h1 * w1.z + h2 * w2v.z + h3 * w3v.z;
          a3 += h0 * w0.w + h1 * w1.w + h2 * w2v.w + h3 * w3v.w;
        }
        float4 o4 = {a0, a1, a2, a3};
        *(float4*)(xprime + (((long)(b * J_N + j0 + jj)) * S_N + s) * 64 + fx) = o4;
      }
    }
  } else {
    // ---- ktqt16: block = (bj, stile); wave w rows stile*16 + w*4 .. +3 ----
    _Float16* stg = (_Float16*)smem;        // [4][4096] halves = 32 KB
    int blk = blockIdx.x - NCOMB;           // 0..767
    int bj = blk / 12, stile = blk - bj * 12;
    int b = bj >> 3, j = bj & 7;
    int w = threadIdx.x >> 6;
    int ig = lane >> 4;                     // i-group 0..3
    int f4 = (lane & 15) * 4;               // f base
    int iK = b * 8 + 2 * ig, iQ = iK + 1;
    float tv = fabsf(temp[0]) * SQRT_SF + 1e-4f;
    float gK = gate_g(esum_p, iK, j, tau, tv);
    float gQ = gate_g(esum_p, iQ, j, tau, tv);
    // lane's fragment slot within a 4096-half tile (m16 filled per row)
    int slotbase = (lane >> 3) * 512 + ((lane >> 1) & 3) * 128 + (lane & 1) * 4;
    for (int rr = 0; rr < 4; rr++) {
      int m16 = w * 4 + rr;
      int s = stile * 16 + m16;
      half4 hk4 = {}, lk4 = {}, hq4 = {}, lq4 = {};
      if (s < S_N) {
        float4 kr = *(const float4*)(proj + ((long)iK * S_N + s) * 64 + f4);
        float4 qr = *(const float4*)(proj + ((long)iQ * S_N + s) * 64 + f4);
        float kv[4] = {kr.x * gK, kr.y * gK, kr.z * gK, kr.w * gK};
        float qv[4] = {qr.x * gQ, qr.y * gQ, qr.z * gQ, qr.w * gQ};
        float mkv = wave_sum(kv[0] + kv[1] + kv[2] + kv[3]) * (1.f / 256.f);
        float mqv = wave_sum(qv[0] + qv[1] + qv[2] + qv[3]) * (1.f / 256.f);
        float vk = 0.f, vq = 0.f;
#pragma unroll
        for (int q = 0; q < 4; q++) {
          float dk = kv[q] - mkv; vk += dk * dk;
          float dq = qv[q] - mqv; vq += dq * dq;
        }
        vk = wave_sum(vk) * (1.f / 256.f);
        vq = wave_sum(vq) * (1.f / 256.f);
        float ik = 1.f / sqrtf(vk + 1e-5f);
        float iq = 1.f / sqrtf(vq + 1e-5f);
#pragma unroll
        for (int q = 0; q < 4; q++) {
          float fk = (kv[q] - mkv) * ik;
          float fq = (qv[q] - mqv) * iq;
          _Float16 hk = (_Float16)fk;
          _Float16 hq = (_Float16)fq;
          hk4[q] = hk; lk4[q] = (_Float16)(fk - (float)hk);
          hq4[q] = hq; lq4[q] = (_Float16)(fq - (float)hq);
        }
      }
      int off = slotbase + m16 * 8;
      *(half4*)&stg[0 * 4096 + off] = hk4;
      *(half4*)&stg[1 * 4096 + off] = lk4;
      *(half4*)&stg[2 * 4096 + off] = hq4;
      *(half4*)&stg[3 * 4096 + off] = lq4;
    }
    __syncthreads();
    // streamed write-out: 4096 halves per array = 512 float4; 2 per thread
    long gb = ((long)bj * 12 + stile) * 4096;
    float4* dk = (float4*)(khi + gb);
    float4* dkl = (float4*)(klo + gb);
    float4* dq = (float4*)(qhi + gb);
    float4* dql = (float4*)(qlo + gb);
    const float4* s0 = (const float4*)(stg + 0 * 4096);
    const float4* s1 = (const float4*)(stg + 1 * 4096);
    const float4* s2 = (const float4*)(stg + 2 * 4096);
    const float4* s3 = (const float4*)(stg + 3 * 4096);
    int t = threadIdx.x;
    dk[t] = s0[t];  dk[t + 256] = s0[t + 256];
    dkl[t] = s1[t]; dkl[t + 256] = s1[t + 256];
    dq[t] = s2[t];  dq[t + 256] = s2[t + 256];
    dql[t] = s3[t]; dql[t + 256] = s3[t + 256];
  }
}

// ---------------- D4. rawfinal768: MFMA -> LDS scores -> softmax -> apply
// Apply/conv/residual phase restructured to float2-per-lane (8 B/lane VMEM,
// G13) with half-wave t-split (h=0: t<96, h=1: t>=96) combined by one
// shfl_xor(32) per accumulator; conv taps split 8/8 via zero-padded 16-tap
// LDS table. w1t stride 196 (16B-aligned, bank-staggered); tail cols zeroed
// so the half-split b128 reads need no guards. Halves VMEM instr count in
// the hot phase and frees the 15-VGPR w3c array.
__global__ void k_rawfinal(const _Float16* __restrict__ khi, const _Float16* __restrict__ klo,
                           const _Float16* __restrict__ qhi, const _Float16* __restrict__ qlo,
                           const float* __restrict__ temp, const float* __restrict__ xprime,
                           const float* __restrict__ comb, const float* __restrict__ w3,
                           const float* __restrict__ alpha, const float* __restrict__ beta,
                           const float* __restrict__ theta, const float* __restrict__ gamma,
                           float* __restrict__ out) {
  __shared__ float w1t[16 * W1STRIDE];   // 12544 B
  __shared__ float w3s[16 * 64];         // 4096 B, [k][o], tap 15 = 0
  int xcd = blockIdx.x & 7;
  int idx = blockIdx.x >> 3;        // 0..95
  int bj = xcd * 8 + idx / 12;
  int stile = idx - (idx / 12) * 12;
  int j = bj & 7;
  int w = threadIdx.x >> 6, lane = threadIdx.x & 63;
  int quad = lane >> 4, m16 = lane & 15;
  long fb = (long)bj * FRAG_BJ + lane * 8;
  // stage w3 transposed [k][o]; tap 15 zeroed
  for (int t = threadIdx.x; t < 16 * 64; t += 256) {
    int k = t >> 6, o = t & 63;
    w3s[t] = (k < KS_N) ? w3[j * 64 * KS_N + o * KS_N + k] : 0.f;
  }
  // zero w1t tail cols 187..195 (survive MFMA store: it guards t < S_N)
  for (int t = threadIdx.x; t < 16 * 9; t += 256) {
    int r = t / 9, c = 187 + (t - r * 9);
    w1t[r * W1STRIDE + c] = 0.f;
  }
  // ---- MFMA: A = this stile's 16 rows; wave w computes tt = 3w..3w+2 ----
  const _Float16* ah_p = khi + fb + (long)stile * 4096;
  const _Float16* al_p = klo + fb + (long)stile * 4096;
  floatx4 acc[3] = {};
  for (int ec = 0; ec < 8; ec++) {
    half8 ah = *(const half8*)(ah_p + ec * 512);
    half8 al = *(const half8*)(al_p + ec * 512);
#pragma unroll
    for (int n = 0; n < 3; n++) {
      long bo = fb + (long)(w * 3 + n) * 4096 + ec * 512;
      half8 bh = *(const half8*)(qhi + bo);
      half8 bl = *(const half8*)(qlo + bo);
      acc[n] = __builtin_amdgcn_mfma_f32_16x16x32_f16(ah, bh, acc[n], 0, 0, 0);
      acc[n] = __builtin_amdgcn_mfma_f32_16x16x32_f16(al, bh, acc[n], 0, 0, 0);
      acc[n] = __builtin_amdgcn_mfma_f32_16x16x32_f16(ah, bl, acc[n], 0, 0, 0);
    }
  }
  float tv = fabsf(temp[0]) * SQRT_SF + 1e-4f;
  float scale = 1.f / (16.f * tv);
#pragma unroll
  for (int n = 0; n < 3; n++) {
    int t = (w * 3 + n) * 16 + m16;  // 0..191
    if (t < S_N) {
#pragma unroll
      for (int r = 0; r < 4; r++)
        w1t[(quad * 4 + r) * W1STRIDE + t] = acc[n][r] * scale;
    }
  }
  __syncthreads();
  // ---- softmax on this wave's 4 rows ----
  int o = lane;
#pragma unroll
  for (int rr = 0; rr < 4; rr++) {
    float* row = &w1t[(w * 4 + rr) * W1STRIDE];
    float v[3];
    float m = -1e30f;
#pragma unroll
    for (int q = 0; q < 3; q++) {
      int t = o + q * 64;
      v[q] = (t < S_N) ? row[t] : -1e30f;
      m = fmaxf(m, v[q]);
    }
    m = wave_max(m);
    float ssum = 0.f;
#pragma unroll
    for (int q = 0; q < 3; q++) {
      int t = o + q * 64;
      float e = (t < S_N) ? expf(v[q] - m) : 0.f;
      v[q] = e;
      ssum += e;
    }
    ssum = wave_sum(ssum);
    float invs = 1.f / ssum;
#pragma unroll
    for (int q = 0; q < 3; q++) {
      int t = o + q * 64;
      if (t < S_N) row[t] = v[q] * invs;
    }
  }
  __syncthreads();
  // ---- apply + conv + residuals: float2 per lane, half-wave t-split ----
  int h = lane >> 5, o2 = lane & 31;
  int o0 = o2 * 2;
  const float* xpg = xprime + (long)bj * (S_N * 64);
  float aa = fabsf(alpha[j]), ba = fabsf(beta[j]), ta = fabsf(theta[j]), gv = gamma[j];
  int s0 = stile * 16;
  int tbase = h * 96;               // h=0: t in [0,96), h=1: [96,192) (cols >=187 are 0)
  float ax[4] = {0.f, 0.f, 0.f, 0.f}, ay[4] = {0.f, 0.f, 0.f, 0.f};
  for (int tb = 0; tb < 96; tb += 4) {
    float4 wv[4];
#pragma unroll
    for (int rr = 0; rr < 4; rr++)
      wv[rr] = *(const float4*)&w1t[(w * 4 + rr) * W1STRIDE + tbase + tb];
#pragma unroll
    for (int q = 0; q < 4; q++) {
      int t = tbase + tb + q;
      int tc = (t < S_N) ? t : S_N - 1;   // weight is 0 for t>=187
      float2 xv = *(const float2*)(xpg + tc * 64 + o0);
      float w0 = ((const float*)&wv[0])[q];
      float w1 = ((const float*)&wv[1])[q];
      float w2 = ((const float*)&wv[2])[q];
      float w3q = ((const float*)&wv[3])[q];
      ax[0] += w0 * xv.x; ay[0] += w0 * xv.y;
      ax[1] += w1 * xv.x; ay[1] += w1 * xv.y;
      ax[2] += w2 * xv.x; ay[2] += w2 * xv.y;
      ax[3] += w3q * xv.x; ay[3] += w3q * xv.y;
    }
  }
  // conv: taps split 8/8 across halves (tap 15 weight = 0)
  float cx[4] = {0.f, 0.f, 0.f, 0.f}, cy[4] = {0.f, 0.f, 0.f, 0.f};
#pragma unroll
  for (int k = 0; k < 8; k++) {
    int kk = h * 8 + k;               // 0..15
    float2 wv3 = *(const float2*)&w3s[kk * 64 + o0];
#pragma unroll
    for (int rr = 0; rr < 4; rr++) {
      int si = s0 + w * 4 + rr + kk - 7;
      int sc = si < 0 ? 0 : (si >= S_N ? S_N - 1 : si);
      float2 xv = *(const float2*)(xpg + sc * 64 + o0);
      bool ok = (si >= 0) && (si < S_N);
      cx[rr] += ok ? wv3.x * xv.x : 0.f;
      cy[rr] += ok ? wv3.y * xv.y : 0.f;
    }
  }
#pragma unroll
  for (int rr = 0; rr < 4; rr++) {
    float px = ba * ax[rr] + ta * cx[rr];
    float py = ba * ay[rr] + ta * cy[rr];
    px += __shfl_xor(px, 32, 64);
    py += __shfl_xor(py, 32, 64);
    int s = s0 + w * 4 + rr;
    if (s < S_N) {
      float2 xs = *(const float2*)(xpg + s * 64 + o0);
      float2 cv = *(const float2*)(comb + ((long)bj * S_N + s) * 64 + o0);
      float2 res;
      res.x = px + aa * xs.x + gv * cv.x;
      res.y = py + aa * xs.y + gv * cv.y;
      if ((h == 0) == (rr < 2))   // h=0 writes rows 0,1; h=1 writes rows 2,3
        *(float2*)(out + ((long)bj * S_N + s) * 64 + o0) = res;
    }
  }
}

extern "C" void kernel_launch(void* const* d_in, const int* in_sizes, int n_in,
                              void* d_out, int out_size, void* d_ws, size_t ws_size,
                              hipStream_t stream) {
  const float* x_in   = (const float*)d_in[0];
  const float* proj   = (const float*)d_in[1];
  const float* sw     = (const float*)d_in[2];
  const float* tau    = (const float*)d_in[3];
  const float* temp   = (const float*)d_in[4];
  const float* omiga  = (const float*)d_in[5];
  const float* W2     = (const float*)d_in[6];
  const float* bparam = (const float*)d_in[7];
  const float* lns    = (const float*)d_in[8];
  const float* lnb    = (const float*)d_in[9];
  const float* alpha  = (const float*)d_in[10];
  const float* beta   = (const float*)d_in[11];
  const float* theta  = (const float*)d_in[12];
  const float* gamma  = (const float*)d_in[13];
  const float* w3     = (const float*)d_in[14];

  float* out = (float*)d_out;
  float* xprime = out + B_N * J_N * S_N * O_N;  // second output, written directly

  float* wsf = (float*)d_ws;
  float* maxp   = wsf;                            // 256 floats
  float* esum_p = wsf + 512;                      // 512*12 floats
  float* act    = wsf + 512 + 512 * NT_SPL;       // 64*8*SF_N floats = 24.5 MB
  const long ACT_N = (long)64 * 8 * SF_N;
  const long FR = (long)64 * FRAG_BJ;             // 3,145,728 halves per frag array
  _Float16* khi = (_Float16*)(act + ACT_N);
  _Float16* klo = khi + FR;
  _Float16* qhi = klo + FR;
  _Float16* qlo = qhi + FR;
  float* comb = (float*)(qlo + FR);

  k_maxabs<<<NMAXP, 256, 0, stream>>>((const float4*)x_in, maxp, (B_N * IN_N * S_N * F_N) / 4);
  k_spline<<<dim3(NT_SPL, 64), 256, 0, stream>>>((const float4*)x_in, sw, omiga, maxp,
                                                 (float4*)act, esum_p);
  k_mid2<<<NCOMB + NKT16, 256, 0, stream>>>((const float4*)act, esum_p, tau, temp, proj,
                                            W2, bparam, lns, lnb, (float4*)comb, xprime,
                                            khi, klo, qhi, qlo);
  k_rawfinal<<<NRF, 256, 0, stream>>>(khi, klo, qhi, qlo, temp, xprime, comb,
                                      w3, alpha, beta, theta, gamma, out);
}